// Round 3
// baseline (2986.728 us; speedup 1.0000x reference)
//
#include <hip/hip_runtime.h>

#define T_LEN 2048
#define HID 64
#define EMB 128
#define NGRP 8                 // sample groups of 32
#define SPG 32                 // samples per group (2 MFMA quads of 16)
#define RSLOT 64               // stream ring slots (steps)
#define HPAD 68                // padded h row (halfs) -> 136B stride, bank-spread

typedef _Float16 half4v __attribute__((ext_vector_type(4)));
typedef _Float16 half8v __attribute__((ext_vector_type(8)));
typedef float f32x4 __attribute__((ext_vector_type(4)));

#if __has_builtin(__builtin_amdgcn_exp2f)
#define EXP2F(x) __builtin_amdgcn_exp2f(x)
#else
#define EXP2F(x) exp2f(x)
#endif
#if __has_builtin(__builtin_amdgcn_rcpf)
#define RCPF(x) __builtin_amdgcn_rcpf(x)
#else
#define RCPF(x) (1.0f / (x))
#endif

#define LOG2E 1.4426950408889634f

// A-fragment: one 16x16x32 K-chunk of a prescaled f32 weight row.
// Lane l holds row m=l&15, k = 4*(l>>4)+{0..3} and +16 (R16-verified layout).
__device__ __forceinline__ half8v ldA(const float* __restrict__ rowp, int kbase,
                                      int g4, float s) {
    float4 lo = *reinterpret_cast<const float4*>(rowp + kbase + g4);
    float4 hi = *reinterpret_cast<const float4*>(rowp + kbase + 16 + g4);
    half8v a = {(_Float16)(lo.x * s), (_Float16)(lo.y * s),
                (_Float16)(lo.z * s), (_Float16)(lo.w * s),
                (_Float16)(hi.x * s), (_Float16)(hi.y * s),
                (_Float16)(hi.z * s), (_Float16)(hi.w * s)};
    return a;
}

// B-fragment: same k pattern from an h vector (per-lane base = its sample row).
__device__ __forceinline__ half8v ldB(const _Float16* base, int kbase, int g4) {
    half4v lo = *reinterpret_cast<const half4v*>(base + kbase + g4);
    half4v hi = *reinterpret_cast<const half4v*>(base + kbase + 16 + g4);
    return __builtin_shufflevector(lo, hi, 0, 1, 2, 3, 4, 5, 6, 7);
}

// ROUND 18: full restructure. R15/16/17 showed: (1) per-sample-per-CU is
// VALU-issue-bound (fdot2 = 32 MAC/cyc/SIMD vs matrix 422); (2) batching
// samples onto MFMA requires spreading the gate VALU work (21 ops/h-elem)
// across many CUs or it becomes the wall; (3) sample-packing per block idles
// CUs. Resolution: pipeline LAYERS across BLOCKS. 24 blocks = 3 layers x 8
// groups(32 samples). Block = 8 waves = 2 independent 16-sample quads
// (2 waves/SIMD -> gates of quad A overlap MFMA of quad B). Per step/wave:
// 16 x mfma_f32_16x16x32_f16 (K=128 = Whh||Wih, bias in C-operand) + gates.
// Layer handoff: global h-stream ring (64 slots) + agent-scope flags:
// producer: stores -> __syncthreads (drains all waves to shared XCD L2) ->
// lane0 release-store flag (cadence 4). Consumer: acquire-poll every 8 steps
// (buffer_inv), per-step register prefetch of next-slot B-frags. Flags are
// zeroed by hipMemsetAsync each launch (stale-flag hazard across graph
// replays). Ring backpressure: producer throttles at 48 slots ahead.
// ws usage: 1KB flags + 2 x 2MB streams.
__global__ __launch_bounds__(512)
void lstm3_pipe(
    const float* __restrict__ x,
    const float* __restrict__ Wih0, const float* __restrict__ Whh0,
    const float* __restrict__ bih0, const float* __restrict__ bhh0,
    const float* __restrict__ Wih1, const float* __restrict__ Whh1,
    const float* __restrict__ bih1, const float* __restrict__ bhh1,
    const float* __restrict__ Wih2, const float* __restrict__ Whh2,
    const float* __restrict__ bih2, const float* __restrict__ bhh2,
    const float* __restrict__ fcW,  const float* __restrict__ fcb,
    float* __restrict__ out, char* __restrict__ ws)
{
    const int bid = blockIdx.x;
    const int lay = bid >> 3;          // 0..2
    const int grp = bid & 7;           // sample group
    const int tid = threadIdx.x;
    const int wv  = tid >> 6;          // 0..7
    const int qd  = wv >> 2;           // quad 0/1 (16 samples each)
    const int q   = wv & 3;            // 16-row slice of each gate
    const int L   = tid & 63;
    const int mr  = L & 15;            // A row-in-tile / B,D col (sample)
    const int lg  = L >> 4;
    const int g4  = 4 * lg;            // k-group base; D rows 4*lg+{0..3}
    const int sl  = 16 * qd + mr;      // sample-local 0..31
    const int sample = SPG * grp + sl;

    __shared__ __align__(16) _Float16 hbuf[2][SPG][HPAD];   // own-layer h dbuf

    int* flags = (int*)ws;
    int* prod0 = flags + grp;          // published by L0
    int* cons0 = flags + 8 + grp;      // published by L1
    int* prod1 = flags + 16 + grp;     // published by L1
    int* cons1 = flags + 24 + grp;     // published by L2
    int* pf_in  = (lay == 2) ? prod1 : prod0;   // polled when lay>0
    int* cf_pub = (lay == 2) ? cons1 : cons0;   // published when lay>0
    int* pf_pub = (lay == 0) ? prod0 : prod1;   // published when lay<2
    int* cf_thr = (lay == 0) ? cons0 : cons1;   // throttle when lay<2

    const size_t STREAM_ELEMS = (size_t)NGRP * RSLOT * SPG * HID;
    _Float16* st0 = (_Float16*)(ws + 1024);
    _Float16* st1 = st0 + STREAM_ELEMS;
    const _Float16* stin = (lay == 2) ? st1 : st0;
    _Float16*      stout = (lay == 0) ? st0 : st1;

    // Zero own h ring (2*32*68 halfs = 2176 dwords).
    for (int i = tid; i < 2176; i += 512)
        reinterpret_cast<unsigned*>(hbuf)[i] = 0u;

    const float sI = -LOG2E, sF = -LOG2E, sG = -2.f * LOG2E, sO = -LOG2E;
    const float scl[4] = {sI, sF, sG, sO};
    const float* Whh = (lay == 0) ? Whh0 : (lay == 1) ? Whh1 : Whh2;
    const float* Wih = (lay == 0) ? Wih0 : (lay == 1) ? Wih1 : Wih2;
    const float* bi  = (lay == 0) ? bih0 : (lay == 1) ? bih1 : bih2;
    const float* bh  = (lay == 0) ? bhh0 : (lay == 1) ? bhh1 : bhh2;

    half8v a4[4][4];                   // [gate][kf]; L0 uses kf 0..1
    f32x4 biasv[4], w0x[4];
    #pragma unroll
    for (int g = 0; g < 4; ++g) {
        const int rowA = 64 * g + 16 * q + mr;     // A (M) row for this lane
        const float* rp = Whh + rowA * 64;
        a4[g][0] = ldA(rp, 0, g4, scl[g]);
        a4[g][1] = ldA(rp, 32, g4, scl[g]);
        if (lay > 0) {
            const float* rp2 = Wih + rowA * 64;
            a4[g][2] = ldA(rp2, 0, g4, scl[g]);
            a4[g][3] = ldA(rp2, 32, g4, scl[g]);
        }
        const int rowD = 64 * g + 16 * q + 4 * lg; // D rows base for this lane
        f32x4 bv, wvv;
        #pragma unroll
        for (int r = 0; r < 4; ++r) bv[r] = (bi[rowD + r] + bh[rowD + r]) * scl[g];
        biasv[g] = bv;
        if (lay == 0) {
            #pragma unroll
            for (int r = 0; r < 4; ++r) wvv[r] = Wih[rowD + r] * scl[g];  // Wih0 [256x1]
            w0x[g] = wvv;
        }
    }

    float cs[4] = {0.f, 0.f, 0.f, 0.f};
    float xv_c = 0.f;
    half8v B2c{}, B3c{};

    __syncthreads();                   // hbuf zero visible

    if (lay == 0) {
        xv_c = x[(size_t)sample * T_LEN];
    } else {
        while (__hip_atomic_load(pf_in, __ATOMIC_ACQUIRE, __HIP_MEMORY_SCOPE_AGENT) < 12)
            __builtin_amdgcn_s_sleep(2);
        const _Float16* sp = stin + (((size_t)grp * RSLOT + 0) * SPG + sl) * HID;
        B2c = ldB(sp, 0, g4);
        B3c = ldB(sp, 32, g4);
    }

    for (int t = 0; t < T_LEN; ++t) {
        // ---- periodic cross-block sync ----
        if ((t & 7) == 0) {
            if (lay > 0) {
                int need = t + 12; if (need > T_LEN) need = T_LEN;
                while (__hip_atomic_load(pf_in, __ATOMIC_ACQUIRE, __HIP_MEMORY_SCOPE_AGENT) < need)
                    __builtin_amdgcn_s_sleep(2);
            }
            if (lay < 2) {
                while (__hip_atomic_load(cf_thr, __ATOMIC_RELAXED, __HIP_MEMORY_SCOPE_AGENT)
                       + (RSLOT - 16) < t)
                    __builtin_amdgcn_s_sleep(2);
            }
        }

        // ---- consume prefetched operands; issue prefetch for t+1 early ----
        float xv = xv_c;
        half8v B2 = B2c, B3 = B3c;
        const int tn = (t < T_LEN - 1) ? t + 1 : T_LEN - 1;
        if (lay == 0) {
            xv_c = x[(size_t)sample * T_LEN + tn];
        } else {
            const _Float16* sp = stin +
                (((size_t)grp * RSLOT + (tn & (RSLOT - 1))) * SPG + sl) * HID;
            B2c = ldB(sp, 0, g4);
            B3c = ldB(sp, 32, g4);
        }

        // ---- own-layer recurrent B frags (h[t-1], parity (t^1)&1) ----
        const _Float16* hb = &hbuf[(t & 1) ^ 1][sl][0];
        half8v B0 = ldB(hb, 0, g4);
        half8v B1 = ldB(hb, 32, g4);

        // ---- MFMA: gates = [Whh||Wih] . [h_own ; h_below] + bias (+ Wih0*x) ----
        f32x4 acc[4];
        #pragma unroll
        for (int g = 0; g < 4; ++g) {
            f32x4 cin = biasv[g];
            if (lay == 0) {
                #pragma unroll
                for (int r = 0; r < 4; ++r) cin[r] = fmaf(w0x[g][r], xv, cin[r]);
            }
            f32x4 a = __builtin_amdgcn_mfma_f32_16x16x32_f16(a4[g][0], B0, cin, 0, 0, 0);
            a = __builtin_amdgcn_mfma_f32_16x16x32_f16(a4[g][1], B1, a, 0, 0, 0);
            if (lay > 0) {
                a = __builtin_amdgcn_mfma_f32_16x16x32_f16(a4[g][2], B2, a, 0, 0, 0);
                a = __builtin_amdgcn_mfma_f32_16x16x32_f16(a4[g][3], B3, a, 0, 0, 0);
            }
            acc[g] = a;
        }

        // ---- gates (exp2-space prescaled) ----
        float hv[4];
        #pragma unroll
        for (int r = 0; r < 4; ++r) {
            float d0 = acc[0][r], d1 = acc[1][r], d2 = acc[2][r], d3 = acc[3][r];
            float ai = RCPF(1.f + EXP2F(d0));
            float af = RCPF(1.f + EXP2F(d1));
            float ag = fmaf(2.f, RCPF(1.f + EXP2F(d2)), -1.f);
            float ao = RCPF(1.f + EXP2F(d3));
            cs[r] = fmaf(af, cs[r], ai * ag);
            float tc = fmaf(2.f, RCPF(1.f + EXP2F(-2.f * LOG2E * cs[r])), -1.f);
            hv[r] = ao * tc;
        }
        half4v h4 = {(_Float16)hv[0], (_Float16)hv[1], (_Float16)hv[2], (_Float16)hv[3]};

        // ---- publish h: own LDS ring + downstream global stream ----
        *reinterpret_cast<half4v*>(&hbuf[t & 1][sl][16 * q + g4]) = h4;
        if (lay < 2) {
            _Float16* op = stout +
                (((size_t)grp * RSLOT + (t & (RSLOT - 1))) * SPG + sl) * HID + 16 * q + g4;
            *reinterpret_cast<half4v*>(op) = h4;
        }

        __syncthreads();   // drains all waves' stores (vmcnt+lgkm) -> shared L2

        if (tid == 0) {
            if (lay < 2 && (t & 3) == 3)
                __hip_atomic_store(pf_pub, t + 1, __ATOMIC_RELEASE, __HIP_MEMORY_SCOPE_AGENT);
            if (lay > 0 && (t & 7) == 7)
                __hip_atomic_store(cf_pub, t + 1, __ATOMIC_RELAXED, __HIP_MEMORY_SCOPE_AGENT);
        }
    }

    // ---- FC epilogue (layer-2 blocks): h2[2047] lives in hbuf[1] ----
    if (lay == 2) {
        for (int idx = tid; idx < SPG * EMB; idx += 512) {
            const int sm = idx >> 7, e = idx & 127;
            float acc2 = fcb[e];
            const _Float16* hf = &hbuf[1][sm][0];
            const float4* W4 = reinterpret_cast<const float4*>(fcW + e * HID);
            #pragma unroll
            for (int k = 0; k < 16; ++k) {
                float4 w4 = W4[k];
                acc2 = fmaf(w4.x, (float)hf[4 * k + 0], acc2);
                acc2 = fmaf(w4.y, (float)hf[4 * k + 1], acc2);
                acc2 = fmaf(w4.z, (float)hf[4 * k + 2], acc2);
                acc2 = fmaf(w4.w, (float)hf[4 * k + 3], acc2);
            }
            out[(size_t)(SPG * grp + sm) * EMB + e] = acc2;
        }
    }
}

extern "C" void kernel_launch(void* const* d_in, const int* in_sizes, int n_in,
                              void* d_out, int out_size, void* d_ws, size_t ws_size,
                              hipStream_t stream) {
    const float* x    = (const float*)d_in[0];
    const float* Wih0 = (const float*)d_in[1];
    const float* Whh0 = (const float*)d_in[2];
    const float* bih0 = (const float*)d_in[3];
    const float* bhh0 = (const float*)d_in[4];
    const float* Wih1 = (const float*)d_in[5];
    const float* Whh1 = (const float*)d_in[6];
    const float* bih1 = (const float*)d_in[7];
    const float* bhh1 = (const float*)d_in[8];
    const float* Wih2 = (const float*)d_in[9];
    const float* Whh2 = (const float*)d_in[10];
    const float* bih2 = (const float*)d_in[11];
    const float* bhh2 = (const float*)d_in[12];
    const float* fcW  = (const float*)d_in[13];
    const float* fcb  = (const float*)d_in[14];
    float* out = (float*)d_out;

    // Zero the handoff flags every launch (streams are flag-gated, so their
    // stale contents are harmless).
    hipMemsetAsync(d_ws, 0, 1024, stream);
    lstm3_pipe<<<dim3(24), dim3(512), 0, stream>>>(
        x, Wih0, Whh0, bih0, bhh0,
        Wih1, Whh1, bih1, bhh1,
        Wih2, Whh2, bih2, bhh2,
        fcW, fcb, out, (char*)d_ws);
}

// Round 4
// 1592.446 us; speedup vs baseline: 1.8756x; 1.8756x over previous
//
#include <hip/hip_runtime.h>

#define T_LEN 2048
#define HID 64
#define EMB 128
#define WD 8                 // steps per window (producer batch period)
#define NWIN (T_LEN / WD)    // 256
#define NPH (NWIN + 4)       // +4 windows of pipeline lag
#define PPAD 68              // padded inner dim of p-buffers (f32)
#define RPAD 72              // padded h-ring row (halfs): 144B stride

typedef _Float16 half2_t __attribute__((ext_vector_type(2)));
typedef _Float16 half4v __attribute__((ext_vector_type(4)));
typedef _Float16 half8v __attribute__((ext_vector_type(8)));
typedef float f32x4 __attribute__((ext_vector_type(4)));
typedef unsigned uint4v __attribute__((ext_vector_type(4)));

#if __has_builtin(__builtin_amdgcn_exp2f)
#define EXP2F(x) __builtin_amdgcn_exp2f(x)
#else
#define EXP2F(x) exp2f(x)
#endif
#if __has_builtin(__builtin_amdgcn_rcpf)
#define RCPF(x) __builtin_amdgcn_rcpf(x)
#else
#define RCPF(x) (1.0f / (x))
#endif

#define LOG2E 1.4426950408889634f

__device__ __forceinline__ float fdot2(unsigned a, unsigned b, float c) {
    return __builtin_amdgcn_fdot2(__builtin_bit_cast(half2_t, a),
                                  __builtin_bit_cast(half2_t, b), c, false);
}

// Half-row 32-MAC dot: 4 weight quads vs 4 gathered-h quads, 4 chains.
__device__ __forceinline__ float dot32(const uint4v* w4, const uint4v* g, float init) {
    float a0 = init, a1 = 0.f, a2 = 0.f, a3 = 0.f;
    #pragma unroll
    for (int q = 0; q < 4; ++q) {
        a0 = fdot2(w4[q][0], g[q][0], a0);
        a1 = fdot2(w4[q][1], g[q][1], a1);
        a2 = fdot2(w4[q][2], g[q][2], a2);
        a3 = fdot2(w4[q][3], g[q][3], a3);
    }
    return (a0 + a1) + (a2 + a3);
}

__device__ __forceinline__ uint4v pack8(float4 a, float4 b, float s) {
    half2_t h0{(_Float16)(a.x * s), (_Float16)(a.y * s)};
    half2_t h1{(_Float16)(a.z * s), (_Float16)(a.w * s)};
    half2_t h2{(_Float16)(b.x * s), (_Float16)(b.y * s)};
    half2_t h3{(_Float16)(b.z * s), (_Float16)(b.w * s)};
    uint4v q;
    q[0] = __builtin_bit_cast(unsigned, h0);
    q[1] = __builtin_bit_cast(unsigned, h1);
    q[2] = __builtin_bit_cast(unsigned, h2);
    q[3] = __builtin_bit_cast(unsigned, h3);
    return q;
}

// ROUND 19: in-block K-split. Post-mortems: R16 -> C-wave issue ~600cyc/step
// (VALUBusy 50% of 1190 wall) is the lever; R17 -> CU-halving loses; R18 ->
// cross-CU handoff costs ~2000cyc/step of sync stall (dead end). R19 keeps
// 256 blocks (1 sample/CU) and splits each C-wave's dot: 6 half-C waves,
// each owning 32 elements with lanes (l, l+32) splitting K 32+32 (64 fdot2
// instead of 128), combined by one __shfl_xor(d,32)/gate. Gates computed
// redundantly in both lane halves (identical -> identical cs). Requires
// per-step visibility of the partner half-wave's h => barrier EVERY step
// (2080 barriers ~ 35us). Producers = R16's window-batched MFMA (verified),
// spread 2 t-tiles/step, with RPAD=72 h-rings (B-frag reads 8-way -> free)
// and PPAD=68 p-buffers. SIMD map (wv&3): S0=L0a+L2a, S1=L0b+L2b,
// S2=L1a+P1, S3=L1b+P2 -> busiest SIMD ~580cyc issue/step vs R15's ~1125.
__global__ __launch_bounds__(512)
__attribute__((amdgpu_waves_per_eu(2, 2)))
void lstm3_split(
    const float* __restrict__ x,
    const float* __restrict__ Wih0, const float* __restrict__ Whh0,
    const float* __restrict__ bih0, const float* __restrict__ bhh0,
    const float* __restrict__ Wih1, const float* __restrict__ Whh1,
    const float* __restrict__ bih1, const float* __restrict__ bhh1,
    const float* __restrict__ Wih2, const float* __restrict__ Whh2,
    const float* __restrict__ bih2, const float* __restrict__ bhh2,
    const float* __restrict__ fcW,  const float* __restrict__ fcb,
    float* __restrict__ out)
{
    const int b   = blockIdx.x;
    const int tid = threadIdx.x;
    const int wv  = tid >> 6;          // 0..7
    const int L   = tid & 63;

    // Roles: wv0/1 = L0a/b, wv2/3 = L1a/b, wv4/5 = L2a/b, wv6 = P1, wv7 = P2.
    const bool isC = (wv < 6);
    const int lay  = wv >> 1;          // 0..2 (C waves)
    const int e    = 32 * (wv & 1) + (L & 31);   // owned element
    const int kb   = (L >> 5) * 32;    // K-half base (0 or 32)
    const bool kh0 = (L < 32);
    const int g4p  = (L >> 4) * 4;     // producer k-group / D-row group
    const int mr   = L & 15;
    const int jj   = L & 7;

    __shared__ __align__(16) _Float16 h0r[16][RPAD];     // 16-step h rings
    __shared__ __align__(16) _Float16 h1r[16][RPAD];
    __shared__ __align__(16) _Float16 h2r[16][RPAD];
    __shared__ __align__(16) float p1b[2][WD][4][PPAD];  // wih1 partials
    __shared__ __align__(16) float p2b[2][WD][4][PPAD];  // wih2 partials
    __shared__ __align__(16) float xs[T_LEN];

    {   // stage x; zero the rings (3 x 576 dwords)
        const float4* xg4 = reinterpret_cast<const float4*>(x + b * T_LEN);
        reinterpret_cast<float4*>(xs)[tid] = xg4[tid];
        for (int i = tid; i < 576; i += 512) {
            reinterpret_cast<unsigned*>(h0r)[i] = 0u;
            reinterpret_cast<unsigned*>(h1r)[i] = 0u;
            reinterpret_cast<unsigned*>(h2r)[i] = 0u;
        }
    }

    const float sI = -LOG2E, sF = -LOG2E, sG = -2.f * LOG2E, sO = -LOG2E;
    const float scl[4] = {sI, sF, sG, sO};

    uint4v w[4][8];                    // C: 4 gates x 4 k-quads; P: 32 A-frags
    float bias4[4] = {0.f, 0.f, 0.f, 0.f};
    float wx4[4]   = {0.f, 0.f, 0.f, 0.f};

    if (isC) {
        const float* Wh = (lay == 0) ? Whh0 : (lay == 1) ? Whh1 : Whh2;
        const float* bi = (lay == 0) ? bih0 : (lay == 1) ? bih1 : bih2;
        const float* bh = (lay == 0) ? bhh0 : (lay == 1) ? bhh1 : bhh2;
        #pragma unroll
        for (int c = 0; c < 4; ++c) {
            const float4* p = reinterpret_cast<const float4*>(Wh + (c * 64 + e) * 64 + kb);
            w[c][0] = pack8(p[0], p[1], scl[c]);
            w[c][1] = pack8(p[2], p[3], scl[c]);
            w[c][2] = pack8(p[4], p[5], scl[c]);
            w[c][3] = pack8(p[6], p[7], scl[c]);
            bias4[c] = (bi[c * 64 + e] + bh[c * 64 + e]) * scl[c];
        }
        if (lay == 0) {
            #pragma unroll
            for (int c = 0; c < 4; ++c) wx4[c] = Wih0[c * 64 + e] * scl[c];
        }
    } else {                           // producer: full Wih as 16 A-tiles x 2
        const float* Wsrc = (wv == 6) ? Wih1 : Wih2;
        #pragma unroll
        for (int tt = 0; tt < 16; ++tt) {
            const float s = scl[tt >> 2];
            const float* rowp = Wsrc + (tt * 16 + mr) * 64;
            #pragma unroll
            for (int kf = 0; kf < 2; ++kf) {
                float4 lo = *reinterpret_cast<const float4*>(rowp + kf * 32 + g4p);
                float4 hi = *reinterpret_cast<const float4*>(rowp + kf * 32 + 16 + g4p);
                half8v a = {(_Float16)(lo.x * s), (_Float16)(lo.y * s),
                            (_Float16)(lo.z * s), (_Float16)(lo.w * s),
                            (_Float16)(hi.x * s), (_Float16)(hi.y * s),
                            (_Float16)(hi.z * s), (_Float16)(hi.w * s)};
                const int idx = tt * 2 + kf;
                w[idx >> 3][idx & 7] = __builtin_bit_cast(uint4v, a);
            }
        }
    }

    _Float16 (*ring)[RPAD] = (lay == 0) ? h0r : (lay == 1) ? h1r : h2r;
    const float* pbase = (lay == 1) ? &p1b[0][0][0][0] : &p2b[0][0][0][0];
    _Float16 (*pring)[RPAD] = (wv == 6) ? h0r : h1r;
    float* pobase = (wv == 6) ? &p1b[0][0][0][0] : &p2b[0][0][0][0];

    float cs = 0.f;                    // cell state: one element per lane
    __syncthreads();

    for (int ph = 0; ph < NPH; ++ph) {
        const int par = ph & 1;
        half8v B0{}, B1{};
        bool act;
        int tbase = 0;
        float* po = nullptr;
        const float* pb = nullptr;

        if (isC) {
            act = (ph >= 2 * lay) && (ph < NWIN + 2 * lay);
            tbase = (ph - 2 * lay) * WD;
            pb = pbase + par * (WD * 4 * PPAD);
        } else {
            const int pp = (wv - 6) * 2;           // P1: 0, P2: 2
            act = (ph >= 1 + pp) && (ph <= NWIN + pp);
            if (act) {                 // B-frags: source window, loop-invariant
                const _Float16* rb = &pring[(par ^ 1) * 8 + jj][0];
                half4v b00 = *reinterpret_cast<const half4v*>(rb + g4p);
                half4v b01 = *reinterpret_cast<const half4v*>(rb + 16 + g4p);
                half4v b10 = *reinterpret_cast<const half4v*>(rb + 32 + g4p);
                half4v b11 = *reinterpret_cast<const half4v*>(rb + 48 + g4p);
                B0 = __builtin_shufflevector(b00, b01, 0, 1, 2, 3, 4, 5, 6, 7);
                B1 = __builtin_shufflevector(b10, b11, 0, 1, 2, 3, 4, 5, 6, 7);
                po = pobase + (par ^ 1) * (WD * 4 * PPAD);
            }
        }

        #pragma unroll
        for (int j = 0; j < WD; ++j) {
            if (isC) {
                if (act) {
                    const int t = tbase + j;
                    const uint4v* hp = reinterpret_cast<const uint4v*>(
                        &ring[(t - 1) & 15][kb]);
                    uint4v g[4] = {hp[0], hp[1], hp[2], hp[3]};
                    float ext[4];
                    if (lay == 0) {
                        const float xv = xs[t];
                        #pragma unroll
                        for (int c = 0; c < 4; ++c) ext[c] = fmaf(wx4[c], xv, bias4[c]);
                    } else {
                        #pragma unroll
                        for (int c = 0; c < 4; ++c)
                            ext[c] = bias4[c] + pb[(j * 4 + c) * PPAD + e];
                    }
                    float d0 = dot32(w[0], g, kh0 ? ext[0] : 0.f);
                    float d1 = dot32(w[1], g, kh0 ? ext[1] : 0.f);
                    float d2 = dot32(w[2], g, kh0 ? ext[2] : 0.f);
                    float d3 = dot32(w[3], g, kh0 ? ext[3] : 0.f);
                    d0 += __shfl_xor(d0, 32, 64);
                    d1 += __shfl_xor(d1, 32, 64);
                    d2 += __shfl_xor(d2, 32, 64);
                    d3 += __shfl_xor(d3, 32, 64);
                    float ai = RCPF(1.f + EXP2F(d0));
                    float af = RCPF(1.f + EXP2F(d1));
                    float ag = fmaf(2.f, RCPF(1.f + EXP2F(d2)), -1.f);
                    float ao = RCPF(1.f + EXP2F(d3));
                    cs = fmaf(af, cs, ai * ag);
                    float tc = fmaf(2.f, RCPF(1.f + EXP2F(-2.f * LOG2E * cs)), -1.f);
                    if (kh0) ring[t & 15][e] = (_Float16)(ao * tc);
                }
            } else if (act) {          // producer: 2 t-tiles per step
                #pragma unroll
                for (int u = 0; u < 2; ++u) {
                    const int tt = 2 * j + u;
                    const int i0 = 2 * tt, i1 = 2 * tt + 1;
                    f32x4 z = {0.f, 0.f, 0.f, 0.f};
                    f32x4 a = __builtin_amdgcn_mfma_f32_16x16x32_f16(
                        __builtin_bit_cast(half8v, w[i0 >> 3][i0 & 7]), B0, z, 0, 0, 0);
                    a = __builtin_amdgcn_mfma_f32_16x16x32_f16(
                        __builtin_bit_cast(half8v, w[i1 >> 3][i1 & 7]), B1, a, 0, 0, 0);
                    if (mr < 8)        // cols 8..15 duplicate
                        *reinterpret_cast<f32x4*>(
                            po + (jj * 4 + (tt >> 2)) * PPAD + (tt & 3) * 16 + g4p) = a;
                }
            }
            __syncthreads();
        }
    }

    // Final FC (f32): h2[2047] lives in ring row 2047 & 15 = 15.
    if (tid < EMB) {
        float acc = fcb[tid];
        const _Float16* hf2 = &h2r[15][0];
        const float4* W4 = reinterpret_cast<const float4*>(fcW + tid * HID);
        #pragma unroll
        for (int k = 0; k < 16; ++k) {
            float4 w4 = W4[k];
            acc = fmaf(w4.x, (float)hf2[4 * k + 0], acc);
            acc = fmaf(w4.y, (float)hf2[4 * k + 1], acc);
            acc = fmaf(w4.z, (float)hf2[4 * k + 2], acc);
            acc = fmaf(w4.w, (float)hf2[4 * k + 3], acc);
        }
        out[b * EMB + tid] = acc;
    }
}

extern "C" void kernel_launch(void* const* d_in, const int* in_sizes, int n_in,
                              void* d_out, int out_size, void* d_ws, size_t ws_size,
                              hipStream_t stream) {
    const float* x    = (const float*)d_in[0];
    const float* Wih0 = (const float*)d_in[1];
    const float* Whh0 = (const float*)d_in[2];
    const float* bih0 = (const float*)d_in[3];
    const float* bhh0 = (const float*)d_in[4];
    const float* Wih1 = (const float*)d_in[5];
    const float* Whh1 = (const float*)d_in[6];
    const float* bih1 = (const float*)d_in[7];
    const float* bhh1 = (const float*)d_in[8];
    const float* Wih2 = (const float*)d_in[9];
    const float* Whh2 = (const float*)d_in[10];
    const float* bih2 = (const float*)d_in[11];
    const float* bhh2 = (const float*)d_in[12];
    const float* fcW  = (const float*)d_in[13];
    const float* fcb  = (const float*)d_in[14];
    float* out = (float*)d_out;

    lstm3_split<<<dim3(256), dim3(512), 0, stream>>>(
        x, Wih0, Whh0, bih0, bhh0,
        Wih1, Whh1, bih1, bhh1,
        Wih2, Whh2, bih2, bhh2,
        fcW, fcb, out);
}

// Round 5
// 1066.607 us; speedup vs baseline: 2.8002x; 1.4930x over previous
//
#include <hip/hip_runtime.h>

#define T_LEN 2048
#define HID 64
#define EMB 128
#define WD 8                 // steps per window (barrier period)
#define NWIN (T_LEN / WD)    // 256
#define NPH (NWIN + 4)       // +4 windows of pipeline lag (C2)

typedef _Float16 half2_t __attribute__((ext_vector_type(2)));
typedef unsigned uint4v __attribute__((ext_vector_type(4)));

#if __has_builtin(__builtin_amdgcn_exp2f)
#define EXP2F(x) __builtin_amdgcn_exp2f(x)
#else
#define EXP2F(x) exp2f(x)
#endif
#if __has_builtin(__builtin_amdgcn_rcpf)
#define RCPF(x) __builtin_amdgcn_rcpf(x)
#else
#define RCPF(x) (1.0f / (x))
#endif

#define LOG2E 1.4426950408889634f

// ROUND 20 core change: v_pk_fma_f16 (2 cyc/inst, 2 MAC) replaces
// v_dot2_f32_f16 (4 cyc/inst, 2 MAC) -> dot issue halved. f16 accumulation,
// 4 chains x 8 deep + pk-add tree, f32 finish. Everything else is R15.
__device__ __forceinline__ half2_t pkfma(unsigned a, unsigned b, half2_t c) {
#if __has_builtin(__builtin_elementwise_fma)
    return __builtin_elementwise_fma(__builtin_bit_cast(half2_t, a),
                                     __builtin_bit_cast(half2_t, b), c);
#else
    return __builtin_bit_cast(half2_t, a) * __builtin_bit_cast(half2_t, b) + c;
#endif
}

// Full-row 64-MAC dot: 8 weight quads vs 8 gathered-h quads, 4 f16x2 chains.
__device__ __forceinline__ float dotrow(const uint4v* w, const uint4v* g, float init) {
    half2_t a0 = {(_Float16)0.f, (_Float16)0.f};
    half2_t a1 = a0, a2 = a0, a3 = a0;
    #pragma unroll
    for (int q = 0; q < 8; ++q) {
        a0 = pkfma(w[q][0], g[q][0], a0);
        a1 = pkfma(w[q][1], g[q][1], a1);
        a2 = pkfma(w[q][2], g[q][2], a2);
        a3 = pkfma(w[q][3], g[q][3], a3);
    }
    half2_t s = (a0 + a1) + (a2 + a3);
    return init + (float)s[0] + (float)s[1];
}

__device__ __forceinline__ uint4v pack8(float4 a, float4 b, float s) {
    half2_t h0{(_Float16)(a.x * s), (_Float16)(a.y * s)};
    half2_t h1{(_Float16)(a.z * s), (_Float16)(a.w * s)};
    half2_t h2{(_Float16)(b.x * s), (_Float16)(b.y * s)};
    half2_t h3{(_Float16)(b.z * s), (_Float16)(b.w * s)};
    uint4v q;
    q[0] = __builtin_bit_cast(unsigned, h0);
    q[1] = __builtin_bit_cast(unsigned, h1);
    q[2] = __builtin_bit_cast(unsigned, h2);
    q[3] = __builtin_bit_cast(unsigned, h3);
    return q;
}

// One 64-float weight row -> 8 packed quads, exp2-space prescaled.
__device__ __forceinline__ void cvt8(const float* __restrict__ Wp, float s, uint4v* dst) {
    const float4* p = reinterpret_cast<const float4*>(Wp);
    #pragma unroll
    for (int k = 0; k < 8; ++k) dst[k] = pack8(p[2 * k], p[2 * k + 1], s);
}

// ROUND 20 = ROUND 15 (974.8us, proven: windowed layer-lag, barrier every
// WD=8 steps, rebalanced producer rows) with the dot MACs moved from
// v_dot2_f32_f16 (4 cyc) to v_pk_fma_f16 (2 cyc, f16 accum). Post-mortems:
// R16 (producer->MFMA): neutral, producers sat in stall slack; R17 (2
// samples/block): interleave works but CU-halving loses 2x; R18 (cross-CU
// layer pipeline): +2000cyc/step sync stall; R19 (K-split + per-step
// barrier): +700cyc/step barrier. Conclusion: R15 is ISSUE-bound (VALUBusy
// 81%) inside single waves, and the only remaining lever is cheaper MAC
// instructions. pk_fma halves dot issue for C waves AND producers; the R15
// SIMD balance (5120 dot-cyc/phase/SIMD) scales uniformly to ~2560.
// Precision: f16 accumulation, 4 chains x 8 + 3 pk_add + f32 finish;
// expected absmax ~2e-3..8e-3 (accepted risk, revert if fail).
//   wv0/1/2 = C0/C1/C2 (4 whh rows, in-lane gates, scalar cell)  [S0/S1/S2]
//   wv4 = wih1_i, wv5 = wih1_f, wv6 = wih1_g (1 row each)        [S0/S1/S2]
//   wv3 = wih1_o + wih2_i (2 rows)                               [S3]
//   wv7 = wih2_{f,g,o}    (3 rows)                               [S3]
// Schedule: phase ph: C0 h0-window ph | p1 for window ph-1 | C1 h1 window
// ph-2 | p2 for window ph-3 | C2 h2 window ph-4. One barrier/phase.
__global__ __launch_bounds__(512)
__attribute__((amdgpu_waves_per_eu(2, 2)))
void lstm3_fused(
    const float* __restrict__ x,
    const float* __restrict__ Wih0, const float* __restrict__ Whh0,
    const float* __restrict__ bih0, const float* __restrict__ bhh0,
    const float* __restrict__ Wih1, const float* __restrict__ Whh1,
    const float* __restrict__ bih1, const float* __restrict__ bhh1,
    const float* __restrict__ Wih2, const float* __restrict__ Whh2,
    const float* __restrict__ bih2, const float* __restrict__ bhh2,
    const float* __restrict__ fcW,  const float* __restrict__ fcb,
    float* __restrict__ out)
{
    const int b   = blockIdx.x;
    const int tid = threadIdx.x;
    const int wv  = tid >> 6;          // 0..7 (wave-uniform role)
    const int L   = tid & 63;          // owned h-index / row-lane

    __shared__ __align__(16) _Float16 h0ring[16][HID];   // 2 windows of h0
    __shared__ __align__(16) _Float16 h1ring[16][HID];   // 2 windows of h1
    __shared__ __align__(16) _Float16 h2ring[2][HID];    // h2 self-ring only
    __shared__ float p1buf[2][WD][4][HID];               // wih1 partials
    __shared__ float p2buf[2][WD][4][HID];               // wih2 partials
    __shared__ __align__(16) float xs[T_LEN];

    // Stage x[b,0,:] (512 float4 by 512 threads); zero the rings.
    {
        const float4* xg4 = reinterpret_cast<const float4*>(x + b * T_LEN);
        reinterpret_cast<float4*>(xs)[tid] = xg4[tid];
        reinterpret_cast<unsigned*>(h0ring)[tid] = 0u;   // 512 dwords
        reinterpret_cast<unsigned*>(h1ring)[tid] = 0u;
        if (tid < 64) reinterpret_cast<unsigned*>(h2ring)[tid] = 0u;
    }

    const float sI = -LOG2E, sF = -LOG2E, sG = -2.f * LOG2E, sO = -LOG2E;
    const float scl[4] = {sI, sF, sG, sO};

    uint4v w[4][8];                    // C: 4 whh rows; wv3: 2; wv7: 3
    float bias4[4] = {0.f, 0.f, 0.f, 0.f};
    float wx4[4]   = {0.f, 0.f, 0.f, 0.f};

    if (wv < 3) {                      // C_l: whh_l all 4 gate rows
        const float* Wh = (wv == 0) ? Whh0 : (wv == 1) ? Whh1 : Whh2;
        const float* bi = (wv == 0) ? bih0 : (wv == 1) ? bih1 : bih2;
        const float* bh = (wv == 0) ? bhh0 : (wv == 1) ? bhh1 : bhh2;
        #pragma unroll
        for (int c = 0; c < 4; ++c) {
            cvt8(Wh + (c * 64 + L) * 64, scl[c], w[c]);
            bias4[c] = (bi[c * 64 + L] + bh[c * 64 + L]) * scl[c];
        }
        if (wv == 0) {
            #pragma unroll
            for (int c = 0; c < 4; ++c) wx4[c] = Wih0[c * 64 + L] * scl[c];
        }
    } else if (wv == 4) {              // P: wih1_i
        cvt8(Wih1 + (  0 + L) * 64, sI, w[0]);
    } else if (wv == 5) {              // P: wih1_f
        cvt8(Wih1 + ( 64 + L) * 64, sF, w[0]);
    } else if (wv == 6) {              // P: wih1_g
        cvt8(Wih1 + (128 + L) * 64, sG, w[0]);
    } else if (wv == 3) {              // P: wih1_o + wih2_i
        cvt8(Wih1 + (192 + L) * 64, sO, w[0]);
        cvt8(Wih2 + (  0 + L) * 64, sI, w[1]);
    } else {                           // wv == 7: wih2_{f,g,o}
        cvt8(Wih2 + ( 64 + L) * 64, sF, w[0]);
        cvt8(Wih2 + (128 + L) * 64, sG, w[1]);
        cvt8(Wih2 + (192 + L) * 64, sO, w[2]);
    }

    float cst = 0.f;                   // cell state (C waves, lane-local)
    __syncthreads();

    for (int ph = 0; ph < NPH; ++ph) {
        const int par = ph & 1;

        if (wv == 0) {
            if (ph < NWIN) {           // h0 window ph
                _Float16* cur = &h0ring[par * 8][0];
                const _Float16* prv = &h0ring[(par ^ 1) * 8][0];
                const int tb = ph * WD;
                #pragma unroll
                for (int j = 0; j < WD; ++j) {
                    const uint4v* hp = reinterpret_cast<const uint4v*>(
                        (j == 0) ? (prv + 7 * HID) : (cur + (j - 1) * HID));
                    uint4v g[8];
                    #pragma unroll
                    for (int k = 0; k < 8; ++k) g[k] = hp[k];
                    float xv = xs[tb + j];
                    float d0 = dotrow(w[0], g, fmaf(wx4[0], xv, bias4[0]));
                    float d1 = dotrow(w[1], g, fmaf(wx4[1], xv, bias4[1]));
                    float d2 = dotrow(w[2], g, fmaf(wx4[2], xv, bias4[2]));
                    float d3 = dotrow(w[3], g, fmaf(wx4[3], xv, bias4[3]));
                    float ai = RCPF(1.f + EXP2F(d0));
                    float af = RCPF(1.f + EXP2F(d1));
                    float ag = fmaf(2.f, RCPF(1.f + EXP2F(d2)), -1.f);
                    float ao = RCPF(1.f + EXP2F(d3));
                    cst = fmaf(af, cst, ai * ag);
                    float tc = fmaf(2.f, RCPF(1.f + EXP2F(-2.f * LOG2E * cst)), -1.f);
                    cur[j * HID + L] = (_Float16)(ao * tc);
                }
            }
        } else if (wv == 1) {
            if (ph >= 2 && ph < NWIN + 2) {    // h1 window ph-2 (p1[par] ready)
                _Float16* cur = &h1ring[par * 8][0];
                const _Float16* prv = &h1ring[(par ^ 1) * 8][0];
                const float (*pb)[4][HID] = p1buf[par];
                #pragma unroll
                for (int j = 0; j < WD; ++j) {
                    const uint4v* hp = reinterpret_cast<const uint4v*>(
                        (j == 0) ? (prv + 7 * HID) : (cur + (j - 1) * HID));
                    uint4v g[8];
                    #pragma unroll
                    for (int k = 0; k < 8; ++k) g[k] = hp[k];
                    float d0 = dotrow(w[0], g, bias4[0] + pb[j][0][L]);
                    float d1 = dotrow(w[1], g, bias4[1] + pb[j][1][L]);
                    float d2 = dotrow(w[2], g, bias4[2] + pb[j][2][L]);
                    float d3 = dotrow(w[3], g, bias4[3] + pb[j][3][L]);
                    float ai = RCPF(1.f + EXP2F(d0));
                    float af = RCPF(1.f + EXP2F(d1));
                    float ag = fmaf(2.f, RCPF(1.f + EXP2F(d2)), -1.f);
                    float ao = RCPF(1.f + EXP2F(d3));
                    cst = fmaf(af, cst, ai * ag);
                    float tc = fmaf(2.f, RCPF(1.f + EXP2F(-2.f * LOG2E * cst)), -1.f);
                    cur[j * HID + L] = (_Float16)(ao * tc);
                }
            }
        } else if (wv == 2) {
            if (ph >= 4) {                     // h2 window ph-4 (p2[par] ready)
                const float (*pb)[4][HID] = p2buf[par];
                #pragma unroll
                for (int j = 0; j < WD; ++j) {
                    const uint4v* hp = reinterpret_cast<const uint4v*>(
                        &h2ring[(j & 1) ^ 1][0]);
                    uint4v g[8];
                    #pragma unroll
                    for (int k = 0; k < 8; ++k) g[k] = hp[k];
                    float d0 = dotrow(w[0], g, bias4[0] + pb[j][0][L]);
                    float d1 = dotrow(w[1], g, bias4[1] + pb[j][1][L]);
                    float d2 = dotrow(w[2], g, bias4[2] + pb[j][2][L]);
                    float d3 = dotrow(w[3], g, bias4[3] + pb[j][3][L]);
                    float ai = RCPF(1.f + EXP2F(d0));
                    float af = RCPF(1.f + EXP2F(d1));
                    float ag = fmaf(2.f, RCPF(1.f + EXP2F(d2)), -1.f);
                    float ao = RCPF(1.f + EXP2F(d3));
                    cst = fmaf(af, cst, ai * ag);
                    float tc = fmaf(2.f, RCPF(1.f + EXP2F(-2.f * LOG2E * cst)), -1.f);
                    h2ring[j & 1][L] = (_Float16)(ao * tc);
                }
            }
        } else {
            // Producer roles. p1 active: ph in [1, NWIN]; p2: ph in [3, NWIN+2].
            const bool p1act = (ph >= 1 && ph < NWIN + 1);
            const bool p2act = (ph >= 3 && ph < NWIN + 3);
            if (wv == 4 || wv == 5 || wv == 6) {
                if (p1act) {                   // one wih1 row vs h0 window ph-1
                    const _Float16* hw = &h0ring[(par ^ 1) * 8][0];
                    float (*po)[4][HID] = p1buf[par ^ 1];
                    const int c0 = wv - 4;     // 4->i(0), 5->f(1), 6->g(2)
                    #pragma unroll
                    for (int j = 0; j < WD; ++j) {
                        const uint4v* hp = reinterpret_cast<const uint4v*>(hw + j * HID);
                        uint4v g[8];
                        #pragma unroll
                        for (int k = 0; k < 8; ++k) g[k] = hp[k];
                        po[j][c0][L] = dotrow(w[0], g, 0.f);
                    }
                }
            } else if (wv == 3) {
                if (p1act) {                   // wih1_o vs h0 window ph-1
                    const _Float16* hw = &h0ring[(par ^ 1) * 8][0];
                    float (*po)[4][HID] = p1buf[par ^ 1];
                    #pragma unroll
                    for (int j = 0; j < WD; ++j) {
                        const uint4v* hp = reinterpret_cast<const uint4v*>(hw + j * HID);
                        uint4v g[8];
                        #pragma unroll
                        for (int k = 0; k < 8; ++k) g[k] = hp[k];
                        po[j][3][L] = dotrow(w[0], g, 0.f);
                    }
                }
                if (p2act) {                   // wih2_i vs h1 window ph-3
                    const _Float16* hw = &h1ring[(par ^ 1) * 8][0];
                    float (*po)[4][HID] = p2buf[par ^ 1];
                    #pragma unroll
                    for (int j = 0; j < WD; ++j) {
                        const uint4v* hp = reinterpret_cast<const uint4v*>(hw + j * HID);
                        uint4v g[8];
                        #pragma unroll
                        for (int k = 0; k < 8; ++k) g[k] = hp[k];
                        po[j][0][L] = dotrow(w[1], g, 0.f);
                    }
                }
            } else {                           // wv == 7: wih2_{f,g,o}
                if (p2act) {
                    const _Float16* hw = &h1ring[(par ^ 1) * 8][0];
                    float (*po)[4][HID] = p2buf[par ^ 1];
                    #pragma unroll
                    for (int j = 0; j < WD; ++j) {
                        const uint4v* hp = reinterpret_cast<const uint4v*>(hw + j * HID);
                        uint4v g[8];
                        #pragma unroll
                        for (int k = 0; k < 8; ++k) g[k] = hp[k];
                        po[j][1][L] = dotrow(w[0], g, 0.f);
                        po[j][2][L] = dotrow(w[1], g, 0.f);
                        po[j][3][L] = dotrow(w[2], g, 0.f);
                    }
                }
            }
        }

        __syncthreads();   // publish window: h rings + p-buffers
    }

    // Final FC (f32): h2[2047] -> slot 2047&1 = 1.
    if (tid < EMB) {
        float acc = fcb[tid];
        const _Float16* hf = &h2ring[1][0];
        const float4* W4 = reinterpret_cast<const float4*>(fcW + tid * HID);
        #pragma unroll
        for (int k = 0; k < 16; ++k) {
            float4 wv4 = W4[k];
            acc = fmaf(wv4.x, (float)hf[4 * k + 0], acc);
            acc = fmaf(wv4.y, (float)hf[4 * k + 1], acc);
            acc = fmaf(wv4.z, (float)hf[4 * k + 2], acc);
            acc = fmaf(wv4.w, (float)hf[4 * k + 3], acc);
        }
        out[b * EMB + tid] = acc;
    }
}

extern "C" void kernel_launch(void* const* d_in, const int* in_sizes, int n_in,
                              void* d_out, int out_size, void* d_ws, size_t ws_size,
                              hipStream_t stream) {
    const float* x    = (const float*)d_in[0];
    const float* Wih0 = (const float*)d_in[1];
    const float* Whh0 = (const float*)d_in[2];
    const float* bih0 = (const float*)d_in[3];
    const float* bhh0 = (const float*)d_in[4];
    const float* Wih1 = (const float*)d_in[5];
    const float* Whh1 = (const float*)d_in[6];
    const float* bih1 = (const float*)d_in[7];
    const float* bhh1 = (const float*)d_in[8];
    const float* Wih2 = (const float*)d_in[9];
    const float* Whh2 = (const float*)d_in[10];
    const float* bih2 = (const float*)d_in[11];
    const float* bhh2 = (const float*)d_in[12];
    const float* fcW  = (const float*)d_in[13];
    const float* fcb  = (const float*)d_in[14];
    float* out = (float*)d_out;

    lstm3_fused<<<dim3(256), dim3(512), 0, stream>>>(
        x, Wih0, Whh0, bih0, bhh0,
        Wih1, Whh1, bih1, bhh1,
        Wih2, Whh2, bih2, bhh2,
        fcW, fcb, out);
}

// Round 6
// 982.793 us; speedup vs baseline: 3.0390x; 1.0853x over previous
//
#include <hip/hip_runtime.h>

#define T_LEN 2048
#define HID 64
#define EMB 128
#define WD 8                 // steps per window (barrier period)
#define NWIN (T_LEN / WD)    // 256
#define NPH (NWIN + 4)       // +4 windows of pipeline lag (C2)

typedef _Float16 half2_t __attribute__((ext_vector_type(2)));
typedef unsigned uint4v __attribute__((ext_vector_type(4)));

#if __has_builtin(__builtin_amdgcn_exp2f)
#define EXP2F(x) __builtin_amdgcn_exp2f(x)
#else
#define EXP2F(x) exp2f(x)
#endif
#if __has_builtin(__builtin_amdgcn_rcpf)
#define RCPF(x) __builtin_amdgcn_rcpf(x)
#else
#define RCPF(x) (1.0f / (x))
#endif

#define LOG2E 1.4426950408889634f

__device__ __forceinline__ float fdot2(unsigned a, unsigned b, float c) {
    return __builtin_amdgcn_fdot2(__builtin_bit_cast(half2_t, a),
                                  __builtin_bit_cast(half2_t, b), c, false);
}

// Full-row 64-MAC dot: 8 weight quads vs 8 gathered-h quads, 4 chains.
__device__ __forceinline__ float dotrow(const uint4v* w, const uint4v* g, float init) {
    float a0 = init, a1 = 0.f, a2 = 0.f, a3 = 0.f;
    #pragma unroll
    for (int q = 0; q < 8; ++q) {
        a0 = fdot2(w[q][0], g[q][0], a0);
        a1 = fdot2(w[q][1], g[q][1], a1);
        a2 = fdot2(w[q][2], g[q][2], a2);
        a3 = fdot2(w[q][3], g[q][3], a3);
    }
    return (a0 + a1) + (a2 + a3);
}

__device__ __forceinline__ uint4v pack8(float4 a, float4 b, float s) {
    half2_t h0{(_Float16)(a.x * s), (_Float16)(a.y * s)};
    half2_t h1{(_Float16)(a.z * s), (_Float16)(a.w * s)};
    half2_t h2{(_Float16)(b.x * s), (_Float16)(b.y * s)};
    half2_t h3{(_Float16)(b.z * s), (_Float16)(b.w * s)};
    uint4v q;
    q[0] = __builtin_bit_cast(unsigned, h0);
    q[1] = __builtin_bit_cast(unsigned, h1);
    q[2] = __builtin_bit_cast(unsigned, h2);
    q[3] = __builtin_bit_cast(unsigned, h3);
    return q;
}

// One 64-float weight row -> 8 packed quads, exp2-space prescaled.
__device__ __forceinline__ void cvt8(const float* __restrict__ Wp, float s, uint4v* dst) {
    const float4* p = reinterpret_cast<const float4*>(Wp);
    #pragma unroll
    for (int k = 0; k < 8; ++k) dst[k] = pack8(p[2 * k], p[2 * k + 1], s);
}

// ROUND 21 = ROUND 15 (974.8us, proven base: windowed layer-lag, barrier
// every WD=8 steps, rebalanced producer rows, fdot2 dots) + s_setprio(1) on
// the three C waves. Post-mortem ledger:
//   R16 producer->MFMA: neutral (producer work lived in C-wave stall slack).
//   R17 2 samples/block: interleave works, CU-halving loses 2x. Dead.
//   R18 cross-CU layer pipe: +2000 cyc/step sync stall. Dead.
//   R19 K-split + per-step barrier: +700 cyc/step barrier. Dead.
//   R20 pk_fma_f16: SAME VALU busy-time as fdot2 (both ~4cyc/2MAC class),
//       longer chain from f16-acc merge tree -> 10% regression. Dead.
// Model: wall = C-wave serial time = 1194 cyc/step (issue ~620 + stall
// ~575). Stall = LDS turnaround + chain latency + ISSUE-ARBITRATION SLOP
// (producer wave wins slots while the chain wave has ready operands).
// T5 regime check: latency-critical wave + throughput wave on one SIMD =
// role diversity -> setprio applies. C waves get prio 1 once; producers 0.
//   wv0/1/2 = C0/C1/C2 (4 whh rows, in-lane gates, scalar cell)  [S0/S1/S2]
//   wv4 = wih1_i, wv5 = wih1_f, wv6 = wih1_g (1 row each)        [S0/S1/S2]
//   wv3 = wih1_o + wih2_i (2 rows)                               [S3]
//   wv7 = wih2_{f,g,o}    (3 rows)                               [S3]
// Schedule: phase ph: C0 h0-window ph | p1 for window ph-1 | C1 h1 window
// ph-2 | p2 for window ph-3 | C2 h2 window ph-4. One barrier/phase.
__global__ __launch_bounds__(512)
__attribute__((amdgpu_waves_per_eu(2, 2)))
void lstm3_fused(
    const float* __restrict__ x,
    const float* __restrict__ Wih0, const float* __restrict__ Whh0,
    const float* __restrict__ bih0, const float* __restrict__ bhh0,
    const float* __restrict__ Wih1, const float* __restrict__ Whh1,
    const float* __restrict__ bih1, const float* __restrict__ bhh1,
    const float* __restrict__ Wih2, const float* __restrict__ Whh2,
    const float* __restrict__ bih2, const float* __restrict__ bhh2,
    const float* __restrict__ fcW,  const float* __restrict__ fcb,
    float* __restrict__ out)
{
    const int b   = blockIdx.x;
    const int tid = threadIdx.x;
    const int wv  = tid >> 6;          // 0..7 (wave-uniform role)
    const int L   = tid & 63;          // owned h-index / row-lane

    __shared__ __align__(16) _Float16 h0ring[16][HID];   // 2 windows of h0
    __shared__ __align__(16) _Float16 h1ring[16][HID];   // 2 windows of h1
    __shared__ __align__(16) _Float16 h2ring[2][HID];    // h2 self-ring only
    __shared__ float p1buf[2][WD][4][HID];               // wih1 partials
    __shared__ float p2buf[2][WD][4][HID];               // wih2 partials
    __shared__ __align__(16) float xs[T_LEN];

    // Stage x[b,0,:] (512 float4 by 512 threads); zero the rings.
    {
        const float4* xg4 = reinterpret_cast<const float4*>(x + b * T_LEN);
        reinterpret_cast<float4*>(xs)[tid] = xg4[tid];
        reinterpret_cast<unsigned*>(h0ring)[tid] = 0u;   // 512 dwords
        reinterpret_cast<unsigned*>(h1ring)[tid] = 0u;
        if (tid < 64) reinterpret_cast<unsigned*>(h2ring)[tid] = 0u;
    }

    const float sI = -LOG2E, sF = -LOG2E, sG = -2.f * LOG2E, sO = -LOG2E;
    const float scl[4] = {sI, sF, sG, sO};

    uint4v w[4][8];                    // C: 4 whh rows; wv3: 2; wv7: 3
    float bias4[4] = {0.f, 0.f, 0.f, 0.f};
    float wx4[4]   = {0.f, 0.f, 0.f, 0.f};

    if (wv < 3) {                      // C_l: whh_l all 4 gate rows
        const float* Wh = (wv == 0) ? Whh0 : (wv == 1) ? Whh1 : Whh2;
        const float* bi = (wv == 0) ? bih0 : (wv == 1) ? bih1 : bih2;
        const float* bh = (wv == 0) ? bhh0 : (wv == 1) ? bhh1 : bhh2;
        #pragma unroll
        for (int c = 0; c < 4; ++c) {
            cvt8(Wh + (c * 64 + L) * 64, scl[c], w[c]);
            bias4[c] = (bi[c * 64 + L] + bh[c * 64 + L]) * scl[c];
        }
        if (wv == 0) {
            #pragma unroll
            for (int c = 0; c < 4; ++c) wx4[c] = Wih0[c * 64 + L] * scl[c];
        }
    } else if (wv == 4) {              // P: wih1_i
        cvt8(Wih1 + (  0 + L) * 64, sI, w[0]);
    } else if (wv == 5) {              // P: wih1_f
        cvt8(Wih1 + ( 64 + L) * 64, sF, w[0]);
    } else if (wv == 6) {              // P: wih1_g
        cvt8(Wih1 + (128 + L) * 64, sG, w[0]);
    } else if (wv == 3) {              // P: wih1_o + wih2_i
        cvt8(Wih1 + (192 + L) * 64, sO, w[0]);
        cvt8(Wih2 + (  0 + L) * 64, sI, w[1]);
    } else {                           // wv == 7: wih2_{f,g,o}
        cvt8(Wih2 + ( 64 + L) * 64, sF, w[0]);
        cvt8(Wih2 + (128 + L) * 64, sG, w[1]);
        cvt8(Wih2 + (192 + L) * 64, sO, w[2]);
    }

    float cst = 0.f;                   // cell state (C waves, lane-local)
    __syncthreads();

    // T5: latency-critical recurrence waves get scheduler priority; the
    // producer (throughput) waves fill genuine stall slots only.
    if (wv < 3) __builtin_amdgcn_s_setprio(1);

    for (int ph = 0; ph < NPH; ++ph) {
        const int par = ph & 1;

        if (wv == 0) {
            if (ph < NWIN) {           // h0 window ph
                _Float16* cur = &h0ring[par * 8][0];
                const _Float16* prv = &h0ring[(par ^ 1) * 8][0];
                const int tb = ph * WD;
                #pragma unroll
                for (int j = 0; j < WD; ++j) {
                    const uint4v* hp = reinterpret_cast<const uint4v*>(
                        (j == 0) ? (prv + 7 * HID) : (cur + (j - 1) * HID));
                    uint4v g[8];
                    #pragma unroll
                    for (int k = 0; k < 8; ++k) g[k] = hp[k];
                    float xv = xs[tb + j];
                    float d0 = dotrow(w[0], g, fmaf(wx4[0], xv, bias4[0]));
                    float d1 = dotrow(w[1], g, fmaf(wx4[1], xv, bias4[1]));
                    float d2 = dotrow(w[2], g, fmaf(wx4[2], xv, bias4[2]));
                    float d3 = dotrow(w[3], g, fmaf(wx4[3], xv, bias4[3]));
                    float ai = RCPF(1.f + EXP2F(d0));
                    float af = RCPF(1.f + EXP2F(d1));
                    float ag = fmaf(2.f, RCPF(1.f + EXP2F(d2)), -1.f);
                    float ao = RCPF(1.f + EXP2F(d3));
                    cst = fmaf(af, cst, ai * ag);
                    float tc = fmaf(2.f, RCPF(1.f + EXP2F(-2.f * LOG2E * cst)), -1.f);
                    cur[j * HID + L] = (_Float16)(ao * tc);
                }
            }
        } else if (wv == 1) {
            if (ph >= 2 && ph < NWIN + 2) {    // h1 window ph-2 (p1[par] ready)
                _Float16* cur = &h1ring[par * 8][0];
                const _Float16* prv = &h1ring[(par ^ 1) * 8][0];
                const float (*pb)[4][HID] = p1buf[par];
                #pragma unroll
                for (int j = 0; j < WD; ++j) {
                    const uint4v* hp = reinterpret_cast<const uint4v*>(
                        (j == 0) ? (prv + 7 * HID) : (cur + (j - 1) * HID));
                    uint4v g[8];
                    #pragma unroll
                    for (int k = 0; k < 8; ++k) g[k] = hp[k];
                    float d0 = dotrow(w[0], g, bias4[0] + pb[j][0][L]);
                    float d1 = dotrow(w[1], g, bias4[1] + pb[j][1][L]);
                    float d2 = dotrow(w[2], g, bias4[2] + pb[j][2][L]);
                    float d3 = dotrow(w[3], g, bias4[3] + pb[j][3][L]);
                    float ai = RCPF(1.f + EXP2F(d0));
                    float af = RCPF(1.f + EXP2F(d1));
                    float ag = fmaf(2.f, RCPF(1.f + EXP2F(d2)), -1.f);
                    float ao = RCPF(1.f + EXP2F(d3));
                    cst = fmaf(af, cst, ai * ag);
                    float tc = fmaf(2.f, RCPF(1.f + EXP2F(-2.f * LOG2E * cst)), -1.f);
                    cur[j * HID + L] = (_Float16)(ao * tc);
                }
            }
        } else if (wv == 2) {
            if (ph >= 4) {                     // h2 window ph-4 (p2[par] ready)
                const float (*pb)[4][HID] = p2buf[par];
                #pragma unroll
                for (int j = 0; j < WD; ++j) {
                    const uint4v* hp = reinterpret_cast<const uint4v*>(
                        &h2ring[(j & 1) ^ 1][0]);
                    uint4v g[8];
                    #pragma unroll
                    for (int k = 0; k < 8; ++k) g[k] = hp[k];
                    float d0 = dotrow(w[0], g, bias4[0] + pb[j][0][L]);
                    float d1 = dotrow(w[1], g, bias4[1] + pb[j][1][L]);
                    float d2 = dotrow(w[2], g, bias4[2] + pb[j][2][L]);
                    float d3 = dotrow(w[3], g, bias4[3] + pb[j][3][L]);
                    float ai = RCPF(1.f + EXP2F(d0));
                    float af = RCPF(1.f + EXP2F(d1));
                    float ag = fmaf(2.f, RCPF(1.f + EXP2F(d2)), -1.f);
                    float ao = RCPF(1.f + EXP2F(d3));
                    cst = fmaf(af, cst, ai * ag);
                    float tc = fmaf(2.f, RCPF(1.f + EXP2F(-2.f * LOG2E * cst)), -1.f);
                    h2ring[j & 1][L] = (_Float16)(ao * tc);
                }
            }
        } else {
            // Producer roles. p1 active: ph in [1, NWIN]; p2: ph in [3, NWIN+2].
            const bool p1act = (ph >= 1 && ph < NWIN + 1);
            const bool p2act = (ph >= 3 && ph < NWIN + 3);
            if (wv == 4 || wv == 5 || wv == 6) {
                if (p1act) {                   // one wih1 row vs h0 window ph-1
                    const _Float16* hw = &h0ring[(par ^ 1) * 8][0];
                    float (*po)[4][HID] = p1buf[par ^ 1];
                    const int c0 = wv - 4;     // 4->i(0), 5->f(1), 6->g(2)
                    #pragma unroll
                    for (int j = 0; j < WD; ++j) {
                        const uint4v* hp = reinterpret_cast<const uint4v*>(hw + j * HID);
                        uint4v g[8];
                        #pragma unroll
                        for (int k = 0; k < 8; ++k) g[k] = hp[k];
                        po[j][c0][L] = dotrow(w[0], g, 0.f);
                    }
                }
            } else if (wv == 3) {
                if (p1act) {                   // wih1_o vs h0 window ph-1
                    const _Float16* hw = &h0ring[(par ^ 1) * 8][0];
                    float (*po)[4][HID] = p1buf[par ^ 1];
                    #pragma unroll
                    for (int j = 0; j < WD; ++j) {
                        const uint4v* hp = reinterpret_cast<const uint4v*>(hw + j * HID);
                        uint4v g[8];
                        #pragma unroll
                        for (int k = 0; k < 8; ++k) g[k] = hp[k];
                        po[j][3][L] = dotrow(w[0], g, 0.f);
                    }
                }
                if (p2act) {                   // wih2_i vs h1 window ph-3
                    const _Float16* hw = &h1ring[(par ^ 1) * 8][0];
                    float (*po)[4][HID] = p2buf[par ^ 1];
                    #pragma unroll
                    for (int j = 0; j < WD; ++j) {
                        const uint4v* hp = reinterpret_cast<const uint4v*>(hw + j * HID);
                        uint4v g[8];
                        #pragma unroll
                        for (int k = 0; k < 8; ++k) g[k] = hp[k];
                        po[j][0][L] = dotrow(w[1], g, 0.f);
                    }
                }
            } else {                           // wv == 7: wih2_{f,g,o}
                if (p2act) {
                    const _Float16* hw = &h1ring[(par ^ 1) * 8][0];
                    float (*po)[4][HID] = p2buf[par ^ 1];
                    #pragma unroll
                    for (int j = 0; j < WD; ++j) {
                        const uint4v* hp = reinterpret_cast<const uint4v*>(hw + j * HID);
                        uint4v g[8];
                        #pragma unroll
                        for (int k = 0; k < 8; ++k) g[k] = hp[k];
                        po[j][1][L] = dotrow(w[0], g, 0.f);
                        po[j][2][L] = dotrow(w[1], g, 0.f);
                        po[j][3][L] = dotrow(w[2], g, 0.f);
                    }
                }
            }
        }

        __syncthreads();   // publish window: h rings + p-buffers
    }

    // Final FC (f32): h2[2047] -> slot 2047&1 = 1.
    if (tid < EMB) {
        float acc = fcb[tid];
        const _Float16* hf = &h2ring[1][0];
        const float4* W4 = reinterpret_cast<const float4*>(fcW + tid * HID);
        #pragma unroll
        for (int k = 0; k < 16; ++k) {
            float4 wv4 = W4[k];
            acc = fmaf(wv4.x, (float)hf[4 * k + 0], acc);
            acc = fmaf(wv4.y, (float)hf[4 * k + 1], acc);
            acc = fmaf(wv4.z, (float)hf[4 * k + 2], acc);
            acc = fmaf(wv4.w, (float)hf[4 * k + 3], acc);
        }
        out[b * EMB + tid] = acc;
    }
}

extern "C" void kernel_launch(void* const* d_in, const int* in_sizes, int n_in,
                              void* d_out, int out_size, void* d_ws, size_t ws_size,
                              hipStream_t stream) {
    const float* x    = (const float*)d_in[0];
    const float* Wih0 = (const float*)d_in[1];
    const float* Whh0 = (const float*)d_in[2];
    const float* bih0 = (const float*)d_in[3];
    const float* bhh0 = (const float*)d_in[4];
    const float* Wih1 = (const float*)d_in[5];
    const float* Whh1 = (const float*)d_in[6];
    const float* bih1 = (const float*)d_in[7];
    const float* bhh1 = (const float*)d_in[8];
    const float* Wih2 = (const float*)d_in[9];
    const float* Whh2 = (const float*)d_in[10];
    const float* bih2 = (const float*)d_in[11];
    const float* bhh2 = (const float*)d_in[12];
    const float* fcW  = (const float*)d_in[13];
    const float* fcb  = (const float*)d_in[14];
    float* out = (float*)d_out;

    lstm3_fused<<<dim3(256), dim3(512), 0, stream>>>(
        x, Wih0, Whh0, bih0, bhh0,
        Wih1, Whh1, bih1, bhh1,
        Wih2, Whh2, bih2, bhh2,
        fcW, fcb, out);
}

// Round 7
// 949.014 us; speedup vs baseline: 3.1472x; 1.0356x over previous
//
#include <hip/hip_runtime.h>

#define T_LEN 2048
#define HID 64
#define EMB 128
#define WD 8                 // steps per window (barrier period)
#define NWIN (T_LEN / WD)    // 256
#define NPH (NWIN + 4)       // +4 windows of pipeline lag (C2)

typedef _Float16 half2_t __attribute__((ext_vector_type(2)));
typedef unsigned uint4v __attribute__((ext_vector_type(4)));

#if __has_builtin(__builtin_amdgcn_exp2f)
#define EXP2F(x) __builtin_amdgcn_exp2f(x)
#else
#define EXP2F(x) exp2f(x)
#endif
#if __has_builtin(__builtin_amdgcn_rcpf)
#define RCPF(x) __builtin_amdgcn_rcpf(x)
#else
#define RCPF(x) (1.0f / (x))
#endif

#define LOG2E 1.4426950408889634f

__device__ __forceinline__ float fdot2(unsigned a, unsigned b, float c) {
    return __builtin_amdgcn_fdot2(__builtin_bit_cast(half2_t, a),
                                  __builtin_bit_cast(half2_t, b), c, false);
}

// Full-row 64-MAC f16 dot (producers): 8 weight quads vs 8 h quads, 4 chains.
__device__ __forceinline__ float dotrow(const uint4v* w, const uint4v* g, float init) {
    float a0 = init, a1 = 0.f, a2 = 0.f, a3 = 0.f;
    #pragma unroll
    for (int q = 0; q < 8; ++q) {
        a0 = fdot2(w[q][0], g[q][0], a0);
        a1 = fdot2(w[q][1], g[q][1], a1);
        a2 = fdot2(w[q][2], g[q][2], a2);
        a3 = fdot2(w[q][3], g[q][3], a3);
    }
    return (a0 + a1) + (a2 + a3);
}

// ROUND 22 core: 64-MAC i8 dot for the recurrent (C-wave) matvec.
// v_dot4_i32_i8 = 4 MAC/inst (same VOP3P issue class as fdot2's 2 MAC)
// -> dot issue 512 -> 256 cyc/step. Exact i32 accumulation; dequant is one
// cvt + fma with the per-row scale folded into the exp2 prescale.
__device__ __forceinline__ float dot64_i8(const uint4v* wq, const uint4v* g,
                                          float fs, float ext) {
    int a0 = 0, a1 = 0, a2 = 0, a3 = 0;
    #pragma unroll
    for (int q = 0; q < 4; ++q) {
        a0 = __builtin_amdgcn_sdot4((int)wq[q][0], (int)g[q][0], a0, false);
        a1 = __builtin_amdgcn_sdot4((int)wq[q][1], (int)g[q][1], a1, false);
        a2 = __builtin_amdgcn_sdot4((int)wq[q][2], (int)g[q][2], a2, false);
        a3 = __builtin_amdgcn_sdot4((int)wq[q][3], (int)g[q][3], a3, false);
    }
    int s = (a0 + a1) + (a2 + a3);
    return fmaf((float)s, fs, ext);
}

__device__ __forceinline__ unsigned pack4i8(float4 v, float s) {
    int q0 = (int)rintf(v.x * s), q1 = (int)rintf(v.y * s);
    int q2 = (int)rintf(v.z * s), q3 = (int)rintf(v.w * s);
    return (unsigned)((q0 & 0xff) | ((q1 & 0xff) << 8) |
                      ((q2 & 0xff) << 16) | ((q3 & 0xff) << 24));
}

// Quantize one 64-float weight row to i8 with dynamic scale 127/max|row|.
// Returns row max; dst = 4 packed quads (16 dwords).
__device__ __forceinline__ float quant_row(const float* __restrict__ Wp, uint4v* dst) {
    const float4* p = reinterpret_cast<const float4*>(Wp);
    float m = 1e-8f;
    #pragma unroll
    for (int k = 0; k < 16; ++k) {
        float4 v = p[k];
        m = fmaxf(m, fmaxf(fmaxf(fabsf(v.x), fabsf(v.y)),
                           fmaxf(fabsf(v.z), fabsf(v.w))));
    }
    const float s = 127.f / m;
    #pragma unroll
    for (int k = 0; k < 4; ++k) {
        uint4v q;
        q[0] = pack4i8(p[4 * k + 0], s);
        q[1] = pack4i8(p[4 * k + 1], s);
        q[2] = pack4i8(p[4 * k + 2], s);
        q[3] = pack4i8(p[4 * k + 3], s);
        dst[k] = q;
    }
    return m;
}

__device__ __forceinline__ uint4v pack8(float4 a, float4 b, float s) {
    half2_t h0{(_Float16)(a.x * s), (_Float16)(a.y * s)};
    half2_t h1{(_Float16)(a.z * s), (_Float16)(a.w * s)};
    half2_t h2{(_Float16)(b.x * s), (_Float16)(b.y * s)};
    half2_t h3{(_Float16)(b.z * s), (_Float16)(b.w * s)};
    uint4v q;
    q[0] = __builtin_bit_cast(unsigned, h0);
    q[1] = __builtin_bit_cast(unsigned, h1);
    q[2] = __builtin_bit_cast(unsigned, h2);
    q[3] = __builtin_bit_cast(unsigned, h3);
    return q;
}

// One 64-float weight row -> 8 packed f16 quads, exp2-space prescaled.
__device__ __forceinline__ void cvt8(const float* __restrict__ Wp, float s, uint4v* dst) {
    const float4* p = reinterpret_cast<const float4*>(Wp);
    #pragma unroll
    for (int k = 0; k < 8; ++k) dst[k] = pack8(p[2 * k], p[2 * k + 1], s);
}

// ROUND 22 = ROUND 15 base (974.8us) with the three C-wave recurrent dots
// moved to i8 v_dot4 (4 MAC/inst vs fdot2's 2 at the same 4-cyc VOP3P
// class). Ledger: R16 producer->MFMA neutral; R17 sample-pack loses CUs;
// R18 cross-CU sync dead; R19 per-step barrier dead; R20 pk_fma same rate
// as fdot2; R21 setprio null. Wall model: 1194 cyc/step = 620 C issue
// (512 = dot) + 130 producer + ~300 chain latency + ~100 barrier. i8 halves
// the dot term -> predicted ~950 cyc/step. Precision: per-gate-row dynamic
// W quant (127/max), h quant at 127 into a parallel i8 ring (f16 ring kept
// for producers + FC); producers stay f16. i32 accumulation exact.
//   wv0/1/2 = C0/C1/C2 (i8 dots)                                 [S0/S1/S2]
//   wv4 = wih1_i, wv5 = wih1_f, wv6 = wih1_g (f16, 1 row each)   [S0/S1/S2]
//   wv3 = wih1_o + wih2_i (2 rows)                               [S3]
//   wv7 = wih2_{f,g,o}    (3 rows)                               [S3]
__global__ __launch_bounds__(512)
__attribute__((amdgpu_waves_per_eu(2, 2)))
void lstm3_fused(
    const float* __restrict__ x,
    const float* __restrict__ Wih0, const float* __restrict__ Whh0,
    const float* __restrict__ bih0, const float* __restrict__ bhh0,
    const float* __restrict__ Wih1, const float* __restrict__ Whh1,
    const float* __restrict__ bih1, const float* __restrict__ bhh1,
    const float* __restrict__ Wih2, const float* __restrict__ Whh2,
    const float* __restrict__ bih2, const float* __restrict__ bhh2,
    const float* __restrict__ fcW,  const float* __restrict__ fcb,
    float* __restrict__ out)
{
    const int b   = blockIdx.x;
    const int tid = threadIdx.x;
    const int wv  = tid >> 6;          // 0..7 (wave-uniform role)
    const int L   = tid & 63;          // owned h-index / row-lane

    __shared__ __align__(16) _Float16 h0ring[16][HID];   // f16: producer feed
    __shared__ __align__(16) _Float16 h1ring[16][HID];
    __shared__ __align__(16) _Float16 h2ring[2][HID];    // f16: FC feed
    __shared__ __align__(16) signed char h0q[16][HID];   // i8: C0 self-feed
    __shared__ __align__(16) signed char h1q[16][HID];   // i8: C1 self-feed
    __shared__ __align__(16) signed char h2q[2][HID];    // i8: C2 self-feed
    __shared__ float p1buf[2][WD][4][HID];               // wih1 partials
    __shared__ float p2buf[2][WD][4][HID];               // wih2 partials
    __shared__ __align__(16) float xs[T_LEN];

    // Stage x[b,0,:]; zero all rings.
    {
        const float4* xg4 = reinterpret_cast<const float4*>(x + b * T_LEN);
        reinterpret_cast<float4*>(xs)[tid] = xg4[tid];
        reinterpret_cast<unsigned*>(h0ring)[tid] = 0u;   // 512 dwords
        reinterpret_cast<unsigned*>(h1ring)[tid] = 0u;
        if (tid < 64) reinterpret_cast<unsigned*>(h2ring)[tid] = 0u;
        if (tid < 256) {
            reinterpret_cast<unsigned*>(h0q)[tid] = 0u;  // 1024B
            reinterpret_cast<unsigned*>(h1q)[tid] = 0u;
        }
        if (tid < 32) reinterpret_cast<unsigned*>(h2q)[tid] = 0u;
    }

    const float sI = -LOG2E, sF = -LOG2E, sG = -2.f * LOG2E, sO = -LOG2E;
    const float scl[4] = {sI, sF, sG, sO};

    uint4v w[4][8];                    // producers: f16 rows (wv3: 2; wv7: 3)
    uint4v wq[4][4];                   // C waves: i8 whh rows
    float bias4[4] = {0.f, 0.f, 0.f, 0.f};
    float wx4[4]   = {0.f, 0.f, 0.f, 0.f};
    float fs4[4]   = {0.f, 0.f, 0.f, 0.f};

    if (wv < 3) {                      // C_l: whh_l all 4 gate rows, i8
        const float* Wh = (wv == 0) ? Whh0 : (wv == 1) ? Whh1 : Whh2;
        const float* bi = (wv == 0) ? bih0 : (wv == 1) ? bih1 : bih2;
        const float* bh = (wv == 0) ? bhh0 : (wv == 1) ? bhh1 : bhh2;
        #pragma unroll
        for (int c = 0; c < 4; ++c) {
            float m = quant_row(Wh + (c * 64 + L) * 64, wq[c]);
            // dequant: whh.h = acc * m/(127*127); fold exp2 prescale; h scale 127.
            fs4[c] = scl[c] * m * (1.f / (127.f * 127.f));
            bias4[c] = (bi[c * 64 + L] + bh[c * 64 + L]) * scl[c];
        }
        if (wv == 0) {
            #pragma unroll
            for (int c = 0; c < 4; ++c) wx4[c] = Wih0[c * 64 + L] * scl[c];
        }
    } else if (wv == 4) {              // P: wih1_i
        cvt8(Wih1 + (  0 + L) * 64, sI, w[0]);
    } else if (wv == 5) {              // P: wih1_f
        cvt8(Wih1 + ( 64 + L) * 64, sF, w[0]);
    } else if (wv == 6) {              // P: wih1_g
        cvt8(Wih1 + (128 + L) * 64, sG, w[0]);
    } else if (wv == 3) {              // P: wih1_o + wih2_i
        cvt8(Wih1 + (192 + L) * 64, sO, w[0]);
        cvt8(Wih2 + (  0 + L) * 64, sI, w[1]);
    } else {                           // wv == 7: wih2_{f,g,o}
        cvt8(Wih2 + ( 64 + L) * 64, sF, w[0]);
        cvt8(Wih2 + (128 + L) * 64, sG, w[1]);
        cvt8(Wih2 + (192 + L) * 64, sO, w[2]);
    }

    float cst = 0.f;                   // cell state (C waves, lane-local)
    __syncthreads();

    for (int ph = 0; ph < NPH; ++ph) {
        const int par = ph & 1;

        if (wv == 0) {
            if (ph < NWIN) {           // h0 window ph
                const int tb = ph * WD;
                #pragma unroll
                for (int j = 0; j < WD; ++j) {
                    const int r  = par * 8 + j;
                    const int rp = (j == 0) ? ((par ^ 1) * 8 + 7) : (r - 1);
                    const uint4v* gq = reinterpret_cast<const uint4v*>(&h0q[rp][0]);
                    uint4v g[4] = {gq[0], gq[1], gq[2], gq[3]};
                    float xv = xs[tb + j];
                    float d0 = dot64_i8(wq[0], g, fs4[0], fmaf(wx4[0], xv, bias4[0]));
                    float d1 = dot64_i8(wq[1], g, fs4[1], fmaf(wx4[1], xv, bias4[1]));
                    float d2 = dot64_i8(wq[2], g, fs4[2], fmaf(wx4[2], xv, bias4[2]));
                    float d3 = dot64_i8(wq[3], g, fs4[3], fmaf(wx4[3], xv, bias4[3]));
                    float ai = RCPF(1.f + EXP2F(d0));
                    float af = RCPF(1.f + EXP2F(d1));
                    float ag = fmaf(2.f, RCPF(1.f + EXP2F(d2)), -1.f);
                    float ao = RCPF(1.f + EXP2F(d3));
                    cst = fmaf(af, cst, ai * ag);
                    float tc = fmaf(2.f, RCPF(1.f + EXP2F(-2.f * LOG2E * cst)), -1.f);
                    float hf = ao * tc;
                    h0q[r][L] = (signed char)(int)rintf(hf * 127.f);  // chain-critical
                    h0ring[r][L] = (_Float16)hf;                      // producer feed
                }
            }
        } else if (wv == 1) {
            if (ph >= 2 && ph < NWIN + 2) {    // h1 window ph-2 (p1[par] ready)
                const float (*pb)[4][HID] = p1buf[par];
                #pragma unroll
                for (int j = 0; j < WD; ++j) {
                    const int r  = par * 8 + j;
                    const int rp = (j == 0) ? ((par ^ 1) * 8 + 7) : (r - 1);
                    const uint4v* gq = reinterpret_cast<const uint4v*>(&h1q[rp][0]);
                    uint4v g[4] = {gq[0], gq[1], gq[2], gq[3]};
                    float d0 = dot64_i8(wq[0], g, fs4[0], bias4[0] + pb[j][0][L]);
                    float d1 = dot64_i8(wq[1], g, fs4[1], bias4[1] + pb[j][1][L]);
                    float d2 = dot64_i8(wq[2], g, fs4[2], bias4[2] + pb[j][2][L]);
                    float d3 = dot64_i8(wq[3], g, fs4[3], bias4[3] + pb[j][3][L]);
                    float ai = RCPF(1.f + EXP2F(d0));
                    float af = RCPF(1.f + EXP2F(d1));
                    float ag = fmaf(2.f, RCPF(1.f + EXP2F(d2)), -1.f);
                    float ao = RCPF(1.f + EXP2F(d3));
                    cst = fmaf(af, cst, ai * ag);
                    float tc = fmaf(2.f, RCPF(1.f + EXP2F(-2.f * LOG2E * cst)), -1.f);
                    float hf = ao * tc;
                    h1q[r][L] = (signed char)(int)rintf(hf * 127.f);
                    h1ring[r][L] = (_Float16)hf;
                }
            }
        } else if (wv == 2) {
            if (ph >= 4) {                     // h2 window ph-4 (p2[par] ready)
                const float (*pb)[4][HID] = p2buf[par];
                #pragma unroll
                for (int j = 0; j < WD; ++j) {
                    const uint4v* gq = reinterpret_cast<const uint4v*>(&h2q[(j & 1) ^ 1][0]);
                    uint4v g[4] = {gq[0], gq[1], gq[2], gq[3]};
                    float d0 = dot64_i8(wq[0], g, fs4[0], bias4[0] + pb[j][0][L]);
                    float d1 = dot64_i8(wq[1], g, fs4[1], bias4[1] + pb[j][1][L]);
                    float d2 = dot64_i8(wq[2], g, fs4[2], bias4[2] + pb[j][2][L]);
                    float d3 = dot64_i8(wq[3], g, fs4[3], bias4[3] + pb[j][3][L]);
                    float ai = RCPF(1.f + EXP2F(d0));
                    float af = RCPF(1.f + EXP2F(d1));
                    float ag = fmaf(2.f, RCPF(1.f + EXP2F(d2)), -1.f);
                    float ao = RCPF(1.f + EXP2F(d3));
                    cst = fmaf(af, cst, ai * ag);
                    float tc = fmaf(2.f, RCPF(1.f + EXP2F(-2.f * LOG2E * cst)), -1.f);
                    float hf = ao * tc;
                    h2q[j & 1][L] = (signed char)(int)rintf(hf * 127.f);
                    h2ring[j & 1][L] = (_Float16)hf;
                }
            }
        } else {
            // Producer roles (f16, unchanged). p1: ph in [1, NWIN]; p2: [3, NWIN+2].
            const bool p1act = (ph >= 1 && ph < NWIN + 1);
            const bool p2act = (ph >= 3 && ph < NWIN + 3);
            if (wv == 4 || wv == 5 || wv == 6) {
                if (p1act) {                   // one wih1 row vs h0 window ph-1
                    const _Float16* hw = &h0ring[(par ^ 1) * 8][0];
                    float (*po)[4][HID] = p1buf[par ^ 1];
                    const int c0 = wv - 4;     // 4->i(0), 5->f(1), 6->g(2)
                    #pragma unroll
                    for (int j = 0; j < WD; ++j) {
                        const uint4v* hp = reinterpret_cast<const uint4v*>(hw + j * HID);
                        uint4v g[8];
                        #pragma unroll
                        for (int k = 0; k < 8; ++k) g[k] = hp[k];
                        po[j][c0][L] = dotrow(w[0], g, 0.f);
                    }
                }
            } else if (wv == 3) {
                if (p1act) {                   // wih1_o vs h0 window ph-1
                    const _Float16* hw = &h0ring[(par ^ 1) * 8][0];
                    float (*po)[4][HID] = p1buf[par ^ 1];
                    #pragma unroll
                    for (int j = 0; j < WD; ++j) {
                        const uint4v* hp = reinterpret_cast<const uint4v*>(hw + j * HID);
                        uint4v g[8];
                        #pragma unroll
                        for (int k = 0; k < 8; ++k) g[k] = hp[k];
                        po[j][3][L] = dotrow(w[0], g, 0.f);
                    }
                }
                if (p2act) {                   // wih2_i vs h1 window ph-3
                    const _Float16* hw = &h1ring[(par ^ 1) * 8][0];
                    float (*po)[4][HID] = p2buf[par ^ 1];
                    #pragma unroll
                    for (int j = 0; j < WD; ++j) {
                        const uint4v* hp = reinterpret_cast<const uint4v*>(hw + j * HID);
                        uint4v g[8];
                        #pragma unroll
                        for (int k = 0; k < 8; ++k) g[k] = hp[k];
                        po[j][0][L] = dotrow(w[1], g, 0.f);
                    }
                }
            } else {                           // wv == 7: wih2_{f,g,o}
                if (p2act) {
                    const _Float16* hw = &h1ring[(par ^ 1) * 8][0];
                    float (*po)[4][HID] = p2buf[par ^ 1];
                    #pragma unroll
                    for (int j = 0; j < WD; ++j) {
                        const uint4v* hp = reinterpret_cast<const uint4v*>(hw + j * HID);
                        uint4v g[8];
                        #pragma unroll
                        for (int k = 0; k < 8; ++k) g[k] = hp[k];
                        po[j][1][L] = dotrow(w[0], g, 0.f);
                        po[j][2][L] = dotrow(w[1], g, 0.f);
                        po[j][3][L] = dotrow(w[2], g, 0.f);
                    }
                }
            }
        }

        __syncthreads();   // publish window: h rings + p-buffers
    }

    // Final FC (f32): h2[2047] -> slot 2047&1 = 1.
    if (tid < EMB) {
        float acc = fcb[tid];
        const _Float16* hf = &h2ring[1][0];
        const float4* W4 = reinterpret_cast<const float4*>(fcW + tid * HID);
        #pragma unroll
        for (int k = 0; k < 16; ++k) {
            float4 wv4 = W4[k];
            acc = fmaf(wv4.x, (float)hf[4 * k + 0], acc);
            acc = fmaf(wv4.y, (float)hf[4 * k + 1], acc);
            acc = fmaf(wv4.z, (float)hf[4 * k + 2], acc);
            acc = fmaf(wv4.w, (float)hf[4 * k + 3], acc);
        }
        out[b * EMB + tid] = acc;
    }
}

extern "C" void kernel_launch(void* const* d_in, const int* in_sizes, int n_in,
                              void* d_out, int out_size, void* d_ws, size_t ws_size,
                              hipStream_t stream) {
    const float* x    = (const float*)d_in[0];
    const float* Wih0 = (const float*)d_in[1];
    const float* Whh0 = (const float*)d_in[2];
    const float* bih0 = (const float*)d_in[3];
    const float* bhh0 = (const float*)d_in[4];
    const float* Wih1 = (const float*)d_in[5];
    const float* Whh1 = (const float*)d_in[6];
    const float* bih1 = (const float*)d_in[7];
    const float* bhh1 = (const float*)d_in[8];
    const float* Wih2 = (const float*)d_in[9];
    const float* Whh2 = (const float*)d_in[10];
    const float* bih2 = (const float*)d_in[11];
    const float* bhh2 = (const float*)d_in[12];
    const float* fcW  = (const float*)d_in[13];
    const float* fcb  = (const float*)d_in[14];
    float* out = (float*)d_out;

    lstm3_fused<<<dim3(256), dim3(512), 0, stream>>>(
        x, Wih0, Whh0, bih0, bhh0,
        Wih1, Whh1, bih1, bhh1,
        Wih2, Whh2, bih2, bhh2,
        fcW, fcb, out);
}

// Round 8
// 948.383 us; speedup vs baseline: 3.1493x; 1.0007x over previous
//
#include <hip/hip_runtime.h>

#define T_LEN 2048
#define HID 64
#define EMB 128
#define WD 8                 // steps per window (barrier period)
#define NWIN (T_LEN / WD)    // 256
#define NPH (NWIN + 4)       // +4 windows of pipeline lag (C2)

typedef _Float16 half2_t __attribute__((ext_vector_type(2)));
typedef unsigned uint4v __attribute__((ext_vector_type(4)));

#if __has_builtin(__builtin_amdgcn_exp2f)
#define EXP2F(x) __builtin_amdgcn_exp2f(x)
#else
#define EXP2F(x) exp2f(x)
#endif
#if __has_builtin(__builtin_amdgcn_rcpf)
#define RCPF(x) __builtin_amdgcn_rcpf(x)
#else
#define RCPF(x) (1.0f / (x))
#endif

#define LOG2E 1.4426950408889634f

__device__ __forceinline__ float fdot2(unsigned a, unsigned b, float c) {
    return __builtin_amdgcn_fdot2(__builtin_bit_cast(half2_t, a),
                                  __builtin_bit_cast(half2_t, b), c, false);
}

// Full-row 64-MAC f16 dot (producers): 8 weight quads vs 8 h quads, 4 chains.
__device__ __forceinline__ float dotrow(const uint4v* w, const uint4v* g, float init) {
    float a0 = init, a1 = 0.f, a2 = 0.f, a3 = 0.f;
    #pragma unroll
    for (int q = 0; q < 8; ++q) {
        a0 = fdot2(w[q][0], g[q][0], a0);
        a1 = fdot2(w[q][1], g[q][1], a1);
        a2 = fdot2(w[q][2], g[q][2], a2);
        a3 = fdot2(w[q][3], g[q][3], a3);
    }
    return (a0 + a1) + (a2 + a3);
}

// ROUND 23 core: recurrent i8 dot fed from SGPR-resident packed h.
// hs[k] is wave-uniform (built by DPP pack + readlane) -> sdot4's one legal
// SGPR source. No LDS round-trip on the recurrence critical path.
__device__ __forceinline__ float dot64_i8s(const uint4v* wq, const int* hs,
                                           float fs, float ext) {
    int a0 = 0, a1 = 0, a2 = 0, a3 = 0;
    #pragma unroll
    for (int q = 0; q < 4; ++q) {
        a0 = __builtin_amdgcn_sdot4((int)wq[q][0], hs[4 * q + 0], a0, false);
        a1 = __builtin_amdgcn_sdot4((int)wq[q][1], hs[4 * q + 1], a1, false);
        a2 = __builtin_amdgcn_sdot4((int)wq[q][2], hs[4 * q + 2], a2, false);
        a3 = __builtin_amdgcn_sdot4((int)wq[q][3], hs[4 * q + 3], a3, false);
    }
    int s = (a0 + a1) + (a2 + a3);
    return fmaf((float)s, fs, ext);
}

// In-register h broadcast: lane L holds byte q(h[L]); after 2 DPP quad-perm
// ORs every lane of quad k holds packed dword h[4k..4k+3]; 16 readlanes put
// the full h vector into SGPRs for next step's dots.
// quad_perm(1,0,3,2) = 0xB1; quad_perm(2,3,0,1) = 0x4E.
__device__ __forceinline__ void pack_h(float hf, int lane, int* hs) {
    int qv = (((int)rintf(hf * 127.f)) & 0xff) << (8 * (lane & 3));
    qv |= __builtin_amdgcn_update_dpp(0, qv, 0xB1, 0xf, 0xf, false);
    qv |= __builtin_amdgcn_update_dpp(0, qv, 0x4E, 0xf, 0xf, false);
    #pragma unroll
    for (int k = 0; k < 16; ++k) hs[k] = __builtin_amdgcn_readlane(qv, 4 * k);
}

__device__ __forceinline__ unsigned pack4i8(float4 v, float s) {
    int q0 = (int)rintf(v.x * s), q1 = (int)rintf(v.y * s);
    int q2 = (int)rintf(v.z * s), q3 = (int)rintf(v.w * s);
    return (unsigned)((q0 & 0xff) | ((q1 & 0xff) << 8) |
                      ((q2 & 0xff) << 16) | ((q3 & 0xff) << 24));
}

// Quantize one 64-float weight row to i8 with dynamic scale 127/max|row|.
__device__ __forceinline__ float quant_row(const float* __restrict__ Wp, uint4v* dst) {
    const float4* p = reinterpret_cast<const float4*>(Wp);
    float m = 1e-8f;
    #pragma unroll
    for (int k = 0; k < 16; ++k) {
        float4 v = p[k];
        m = fmaxf(m, fmaxf(fmaxf(fabsf(v.x), fabsf(v.y)),
                           fmaxf(fabsf(v.z), fabsf(v.w))));
    }
    const float s = 127.f / m;
    #pragma unroll
    for (int k = 0; k < 4; ++k) {
        uint4v q;
        q[0] = pack4i8(p[4 * k + 0], s);
        q[1] = pack4i8(p[4 * k + 1], s);
        q[2] = pack4i8(p[4 * k + 2], s);
        q[3] = pack4i8(p[4 * k + 3], s);
        dst[k] = q;
    }
    return m;
}

__device__ __forceinline__ uint4v pack8(float4 a, float4 b, float s) {
    half2_t h0{(_Float16)(a.x * s), (_Float16)(a.y * s)};
    half2_t h1{(_Float16)(a.z * s), (_Float16)(a.w * s)};
    half2_t h2{(_Float16)(b.x * s), (_Float16)(b.y * s)};
    half2_t h3{(_Float16)(b.z * s), (_Float16)(b.w * s)};
    uint4v q;
    q[0] = __builtin_bit_cast(unsigned, h0);
    q[1] = __builtin_bit_cast(unsigned, h1);
    q[2] = __builtin_bit_cast(unsigned, h2);
    q[3] = __builtin_bit_cast(unsigned, h3);
    return q;
}

// One 64-float weight row -> 8 packed f16 quads, exp2-space prescaled.
__device__ __forceinline__ void cvt8(const float* __restrict__ Wp, float s, uint4v* dst) {
    const float4* p = reinterpret_cast<const float4*>(Wp);
    #pragma unroll
    for (int k = 0; k < 8; ++k) dst[k] = pack8(p[2 * k], p[2 * k + 1], s);
}

// ROUND 23 = ROUND 22 (949us) with the recurrent h kept IN REGISTERS
// (SGPR broadcast) instead of an LDS self-ring. R22 post-mortem: dot issue
// halved but wall moved only 2.6% -> chain is LATENCY-bound; the removable
// latency is the ~120cyc LDS write->read turnaround between h[t] and the
// t+1 dots. Fix: quantize h in-lane, DPP quad-perm OR pack (2 steps), 16x
// v_readlane -> SGPRs; sdot4 takes the SGPR directly (1 SGPR src legal).
// i8 rings deleted; f16 rings kept (producer/FC feed, off-critical).
// Numerics identical to R22 -> absmax must be exactly 1.464844e-3.
// Ledger: R16 MFMA-producers neutral; R17 CU-halving loses; R18 cross-CU
// dead; R19 per-step barrier dead; R20 pk_fma same rate; R21 setprio null;
// R22 i8 dots -2.6% (latency-bound revealed).
//   wv0/1/2 = C0/C1/C2 (i8 dots, SGPR h)                         [S0/S1/S2]
//   wv4 = wih1_i, wv5 = wih1_f, wv6 = wih1_g (f16, 1 row each)   [S0/S1/S2]
//   wv3 = wih1_o + wih2_i (2 rows)                               [S3]
//   wv7 = wih2_{f,g,o}    (3 rows)                               [S3]
__global__ __launch_bounds__(512)
__attribute__((amdgpu_waves_per_eu(2, 2)))
void lstm3_fused(
    const float* __restrict__ x,
    const float* __restrict__ Wih0, const float* __restrict__ Whh0,
    const float* __restrict__ bih0, const float* __restrict__ bhh0,
    const float* __restrict__ Wih1, const float* __restrict__ Whh1,
    const float* __restrict__ bih1, const float* __restrict__ bhh1,
    const float* __restrict__ Wih2, const float* __restrict__ Whh2,
    const float* __restrict__ bih2, const float* __restrict__ bhh2,
    const float* __restrict__ fcW,  const float* __restrict__ fcb,
    float* __restrict__ out)
{
    const int b   = blockIdx.x;
    const int tid = threadIdx.x;
    const int wv  = tid >> 6;          // 0..7 (wave-uniform role)
    const int L   = tid & 63;          // owned h-index / row-lane

    __shared__ __align__(16) _Float16 h0ring[16][HID];   // f16: producer feed
    __shared__ __align__(16) _Float16 h1ring[16][HID];
    __shared__ __align__(16) _Float16 h2ring[2][HID];    // f16: FC feed
    __shared__ float p1buf[2][WD][4][HID];               // wih1 partials
    __shared__ float p2buf[2][WD][4][HID];               // wih2 partials
    __shared__ __align__(16) float xs[T_LEN];

    // Stage x[b,0,:]; zero the f16 rings.
    {
        const float4* xg4 = reinterpret_cast<const float4*>(x + b * T_LEN);
        reinterpret_cast<float4*>(xs)[tid] = xg4[tid];
        reinterpret_cast<unsigned*>(h0ring)[tid] = 0u;   // 512 dwords
        reinterpret_cast<unsigned*>(h1ring)[tid] = 0u;
        if (tid < 64) reinterpret_cast<unsigned*>(h2ring)[tid] = 0u;
    }

    const float sI = -LOG2E, sF = -LOG2E, sG = -2.f * LOG2E, sO = -LOG2E;
    const float scl[4] = {sI, sF, sG, sO};

    uint4v w[4][8];                    // producers: f16 rows (wv3: 2; wv7: 3)
    uint4v wq[4][4];                   // C waves: i8 whh rows
    float bias4[4] = {0.f, 0.f, 0.f, 0.f};
    float wx4[4]   = {0.f, 0.f, 0.f, 0.f};
    float fs4[4]   = {0.f, 0.f, 0.f, 0.f};

    if (wv < 3) {                      // C_l: whh_l all 4 gate rows, i8
        const float* Wh = (wv == 0) ? Whh0 : (wv == 1) ? Whh1 : Whh2;
        const float* bi = (wv == 0) ? bih0 : (wv == 1) ? bih1 : bih2;
        const float* bh = (wv == 0) ? bhh0 : (wv == 1) ? bhh1 : bhh2;
        #pragma unroll
        for (int c = 0; c < 4; ++c) {
            float m = quant_row(Wh + (c * 64 + L) * 64, wq[c]);
            fs4[c] = scl[c] * m * (1.f / (127.f * 127.f));
            bias4[c] = (bi[c * 64 + L] + bh[c * 64 + L]) * scl[c];
        }
        if (wv == 0) {
            #pragma unroll
            for (int c = 0; c < 4; ++c) wx4[c] = Wih0[c * 64 + L] * scl[c];
        }
    } else if (wv == 4) {              // P: wih1_i
        cvt8(Wih1 + (  0 + L) * 64, sI, w[0]);
    } else if (wv == 5) {              // P: wih1_f
        cvt8(Wih1 + ( 64 + L) * 64, sF, w[0]);
    } else if (wv == 6) {              // P: wih1_g
        cvt8(Wih1 + (128 + L) * 64, sG, w[0]);
    } else if (wv == 3) {              // P: wih1_o + wih2_i
        cvt8(Wih1 + (192 + L) * 64, sO, w[0]);
        cvt8(Wih2 + (  0 + L) * 64, sI, w[1]);
    } else {                           // wv == 7: wih2_{f,g,o}
        cvt8(Wih2 + ( 64 + L) * 64, sF, w[0]);
        cvt8(Wih2 + (128 + L) * 64, sG, w[1]);
        cvt8(Wih2 + (192 + L) * 64, sO, w[2]);
    }

    float cst = 0.f;                   // cell state (C waves, lane-local)
    int hs[16];                        // packed i8 h[t-1], wave-uniform
    #pragma unroll
    for (int k = 0; k < 16; ++k) hs[k] = 0;

    __syncthreads();

    for (int ph = 0; ph < NPH; ++ph) {
        const int par = ph & 1;

        if (wv == 0) {
            if (ph < NWIN) {           // h0 window ph
                const int tb = ph * WD;
                #pragma unroll
                for (int j = 0; j < WD; ++j) {
                    const int r = par * 8 + j;
                    float xv = xs[tb + j];
                    float d0 = dot64_i8s(wq[0], hs, fs4[0], fmaf(wx4[0], xv, bias4[0]));
                    float d1 = dot64_i8s(wq[1], hs, fs4[1], fmaf(wx4[1], xv, bias4[1]));
                    float d2 = dot64_i8s(wq[2], hs, fs4[2], fmaf(wx4[2], xv, bias4[2]));
                    float d3 = dot64_i8s(wq[3], hs, fs4[3], fmaf(wx4[3], xv, bias4[3]));
                    float ai = RCPF(1.f + EXP2F(d0));
                    float af = RCPF(1.f + EXP2F(d1));
                    float ag = fmaf(2.f, RCPF(1.f + EXP2F(d2)), -1.f);
                    float ao = RCPF(1.f + EXP2F(d3));
                    cst = fmaf(af, cst, ai * ag);
                    float tc = fmaf(2.f, RCPF(1.f + EXP2F(-2.f * LOG2E * cst)), -1.f);
                    float hf = ao * tc;
                    h0ring[r][L] = (_Float16)hf;       // producer feed
                    pack_h(hf, L, hs);                  // chain: regs only
                }
            }
        } else if (wv == 1) {
            if (ph >= 2 && ph < NWIN + 2) {    // h1 window ph-2 (p1[par] ready)
                const float (*pb)[4][HID] = p1buf[par];
                #pragma unroll
                for (int j = 0; j < WD; ++j) {
                    const int r = par * 8 + j;
                    float d0 = dot64_i8s(wq[0], hs, fs4[0], bias4[0] + pb[j][0][L]);
                    float d1 = dot64_i8s(wq[1], hs, fs4[1], bias4[1] + pb[j][1][L]);
                    float d2 = dot64_i8s(wq[2], hs, fs4[2], bias4[2] + pb[j][2][L]);
                    float d3 = dot64_i8s(wq[3], hs, fs4[3], bias4[3] + pb[j][3][L]);
                    float ai = RCPF(1.f + EXP2F(d0));
                    float af = RCPF(1.f + EXP2F(d1));
                    float ag = fmaf(2.f, RCPF(1.f + EXP2F(d2)), -1.f);
                    float ao = RCPF(1.f + EXP2F(d3));
                    cst = fmaf(af, cst, ai * ag);
                    float tc = fmaf(2.f, RCPF(1.f + EXP2F(-2.f * LOG2E * cst)), -1.f);
                    float hf = ao * tc;
                    h1ring[r][L] = (_Float16)hf;
                    pack_h(hf, L, hs);
                }
            }
        } else if (wv == 2) {
            if (ph >= 4) {                     // h2 window ph-4 (p2[par] ready)
                const float (*pb)[4][HID] = p2buf[par];
                #pragma unroll
                for (int j = 0; j < WD; ++j) {
                    float d0 = dot64_i8s(wq[0], hs, fs4[0], bias4[0] + pb[j][0][L]);
                    float d1 = dot64_i8s(wq[1], hs, fs4[1], bias4[1] + pb[j][1][L]);
                    float d2 = dot64_i8s(wq[2], hs, fs4[2], bias4[2] + pb[j][2][L]);
                    float d3 = dot64_i8s(wq[3], hs, fs4[3], bias4[3] + pb[j][3][L]);
                    float ai = RCPF(1.f + EXP2F(d0));
                    float af = RCPF(1.f + EXP2F(d1));
                    float ag = fmaf(2.f, RCPF(1.f + EXP2F(d2)), -1.f);
                    float ao = RCPF(1.f + EXP2F(d3));
                    cst = fmaf(af, cst, ai * ag);
                    float tc = fmaf(2.f, RCPF(1.f + EXP2F(-2.f * LOG2E * cst)), -1.f);
                    float hf = ao * tc;
                    h2ring[j & 1][L] = (_Float16)hf;   // FC feed
                    pack_h(hf, L, hs);
                }
            }
        } else {
            // Producer roles (f16, unchanged). p1: ph in [1, NWIN]; p2: [3, NWIN+2].
            const bool p1act = (ph >= 1 && ph < NWIN + 1);
            const bool p2act = (ph >= 3 && ph < NWIN + 3);
            if (wv == 4 || wv == 5 || wv == 6) {
                if (p1act) {                   // one wih1 row vs h0 window ph-1
                    const _Float16* hw = &h0ring[(par ^ 1) * 8][0];
                    float (*po)[4][HID] = p1buf[par ^ 1];
                    const int c0 = wv - 4;     // 4->i(0), 5->f(1), 6->g(2)
                    #pragma unroll
                    for (int j = 0; j < WD; ++j) {
                        const uint4v* hp = reinterpret_cast<const uint4v*>(hw + j * HID);
                        uint4v g[8];
                        #pragma unroll
                        for (int k = 0; k < 8; ++k) g[k] = hp[k];
                        po[j][c0][L] = dotrow(w[0], g, 0.f);
                    }
                }
            } else if (wv == 3) {
                if (p1act) {                   // wih1_o vs h0 window ph-1
                    const _Float16* hw = &h0ring[(par ^ 1) * 8][0];
                    float (*po)[4][HID] = p1buf[par ^ 1];
                    #pragma unroll
                    for (int j = 0; j < WD; ++j) {
                        const uint4v* hp = reinterpret_cast<const uint4v*>(hw + j * HID);
                        uint4v g[8];
                        #pragma unroll
                        for (int k = 0; k < 8; ++k) g[k] = hp[k];
                        po[j][3][L] = dotrow(w[0], g, 0.f);
                    }
                }
                if (p2act) {                   // wih2_i vs h1 window ph-3
                    const _Float16* hw = &h1ring[(par ^ 1) * 8][0];
                    float (*po)[4][HID] = p2buf[par ^ 1];
                    #pragma unroll
                    for (int j = 0; j < WD; ++j) {
                        const uint4v* hp = reinterpret_cast<const uint4v*>(hw + j * HID);
                        uint4v g[8];
                        #pragma unroll
                        for (int k = 0; k < 8; ++k) g[k] = hp[k];
                        po[j][0][L] = dotrow(w[1], g, 0.f);
                    }
                }
            } else {                           // wv == 7: wih2_{f,g,o}
                if (p2act) {
                    const _Float16* hw = &h1ring[(par ^ 1) * 8][0];
                    float (*po)[4][HID] = p2buf[par ^ 1];
                    #pragma unroll
                    for (int j = 0; j < WD; ++j) {
                        const uint4v* hp = reinterpret_cast<const uint4v*>(hw + j * HID);
                        uint4v g[8];
                        #pragma unroll
                        for (int k = 0; k < 8; ++k) g[k] = hp[k];
                        po[j][1][L] = dotrow(w[0], g, 0.f);
                        po[j][2][L] = dotrow(w[1], g, 0.f);
                        po[j][3][L] = dotrow(w[2], g, 0.f);
                    }
                }
            }
        }

        __syncthreads();   // publish window: h rings + p-buffers
    }

    // Final FC (f32): h2[2047] -> slot 2047&1 = 1.
    if (tid < EMB) {
        float acc = fcb[tid];
        const _Float16* hf = &h2ring[1][0];
        const float4* W4 = reinterpret_cast<const float4*>(fcW + tid * HID);
        #pragma unroll
        for (int k = 0; k < 16; ++k) {
            float4 wv4 = W4[k];
            acc = fmaf(wv4.x, (float)hf[4 * k + 0], acc);
            acc = fmaf(wv4.y, (float)hf[4 * k + 1], acc);
            acc = fmaf(wv4.z, (float)hf[4 * k + 2], acc);
            acc = fmaf(wv4.w, (float)hf[4 * k + 3], acc);
        }
        out[b * EMB + tid] = acc;
    }
}

extern "C" void kernel_launch(void* const* d_in, const int* in_sizes, int n_in,
                              void* d_out, int out_size, void* d_ws, size_t ws_size,
                              hipStream_t stream) {
    const float* x    = (const float*)d_in[0];
    const float* Wih0 = (const float*)d_in[1];
    const float* Whh0 = (const float*)d_in[2];
    const float* bih0 = (const float*)d_in[3];
    const float* bhh0 = (const float*)d_in[4];
    const float* Wih1 = (const float*)d_in[5];
    const float* Whh1 = (const float*)d_in[6];
    const float* bih1 = (const float*)d_in[7];
    const float* bhh1 = (const float*)d_in[8];
    const float* Wih2 = (const float*)d_in[9];
    const float* Whh2 = (const float*)d_in[10];
    const float* bih2 = (const float*)d_in[11];
    const float* bhh2 = (const float*)d_in[12];
    const float* fcW  = (const float*)d_in[13];
    const float* fcb  = (const float*)d_in[14];
    float* out = (float*)d_out;

    lstm3_fused<<<dim3(256), dim3(512), 0, stream>>>(
        x, Wih0, Whh0, bih0, bhh0,
        Wih1, Whh1, bih1, bhh1,
        Wih2, Whh2, bih2, bhh2,
        fcW, fcb, out);
}

// Round 9
// 878.598 us; speedup vs baseline: 3.3994x; 1.0794x over previous
//
#include <hip/hip_runtime.h>

#define T_LEN 2048
#define HID 64
#define EMB 128
#define WD 8                 // steps per window (barrier period)
#define NWIN (T_LEN / WD)    // 256
#define NPH (NWIN + 4)       // +4 windows of pipeline lag (C2)

typedef _Float16 half2_t __attribute__((ext_vector_type(2)));
typedef unsigned uint4v __attribute__((ext_vector_type(4)));

#if __has_builtin(__builtin_amdgcn_exp2f)
#define EXP2F(x) __builtin_amdgcn_exp2f(x)
#else
#define EXP2F(x) exp2f(x)
#endif
#if __has_builtin(__builtin_amdgcn_rcpf)
#define RCPF(x) __builtin_amdgcn_rcpf(x)
#else
#define RCPF(x) (1.0f / (x))
#endif

#define LOG2E 1.4426950408889634f

// Recurrent i8 dot fed from SGPR-resident packed h (R23-verified).
__device__ __forceinline__ float dot64_i8s(const uint4v* wq, const int* hs,
                                           float fs, float ext) {
    int a0 = 0, a1 = 0, a2 = 0, a3 = 0;
    #pragma unroll
    for (int q = 0; q < 4; ++q) {
        a0 = __builtin_amdgcn_sdot4((int)wq[q][0], hs[4 * q + 0], a0, false);
        a1 = __builtin_amdgcn_sdot4((int)wq[q][1], hs[4 * q + 1], a1, false);
        a2 = __builtin_amdgcn_sdot4((int)wq[q][2], hs[4 * q + 2], a2, false);
        a3 = __builtin_amdgcn_sdot4((int)wq[q][3], hs[4 * q + 3], a3, false);
    }
    int s = (a0 + a1) + (a2 + a3);
    return fmaf((float)s, fs, ext);
}

// Producer i8 dot: weights (per-lane row) vs wave-uniform h quads from LDS.
__device__ __forceinline__ float dot64_i8v(const uint4v* wq, const uint4v* g,
                                           float fs) {
    int a0 = 0, a1 = 0, a2 = 0, a3 = 0;
    #pragma unroll
    for (int q = 0; q < 4; ++q) {
        a0 = __builtin_amdgcn_sdot4((int)wq[q][0], (int)g[q][0], a0, false);
        a1 = __builtin_amdgcn_sdot4((int)wq[q][1], (int)g[q][1], a1, false);
        a2 = __builtin_amdgcn_sdot4((int)wq[q][2], (int)g[q][2], a2, false);
        a3 = __builtin_amdgcn_sdot4((int)wq[q][3], (int)g[q][3], a3, false);
    }
    int s = (a0 + a1) + (a2 + a3);
    return (float)s * fs;
}

// In-register h broadcast (R23-verified): lane L contributes byte qb at slot
// L&3; 2 DPP quad-perm ORs assemble the packed dword in every lane of each
// quad; 16 readlanes lift h to SGPRs. quad_perm(1,0,3,2)=0xB1; (2,3,0,1)=0x4E.
__device__ __forceinline__ void pack_hq(int qb, int lane, int* hs) {
    int qv = (qb & 0xff) << (8 * (lane & 3));
    qv |= __builtin_amdgcn_update_dpp(0, qv, 0xB1, 0xf, 0xf, false);
    qv |= __builtin_amdgcn_update_dpp(0, qv, 0x4E, 0xf, 0xf, false);
    #pragma unroll
    for (int k = 0; k < 16; ++k) hs[k] = __builtin_amdgcn_readlane(qv, 4 * k);
}

__device__ __forceinline__ unsigned pack4i8(float4 v, float s) {
    int q0 = (int)rintf(v.x * s), q1 = (int)rintf(v.y * s);
    int q2 = (int)rintf(v.z * s), q3 = (int)rintf(v.w * s);
    return (unsigned)((q0 & 0xff) | ((q1 & 0xff) << 8) |
                      ((q2 & 0xff) << 16) | ((q3 & 0xff) << 24));
}

// Quantize one 64-float weight row to i8, dynamic scale 127/max|row|.
__device__ __forceinline__ float quant_row(const float* __restrict__ Wp, uint4v* dst) {
    const float4* p = reinterpret_cast<const float4*>(Wp);
    float m = 1e-8f;
    #pragma unroll
    for (int k = 0; k < 16; ++k) {
        float4 v = p[k];
        m = fmaxf(m, fmaxf(fmaxf(fabsf(v.x), fabsf(v.y)),
                           fmaxf(fabsf(v.z), fabsf(v.w))));
    }
    const float s = 127.f / m;
    #pragma unroll
    for (int k = 0; k < 4; ++k) {
        uint4v q;
        q[0] = pack4i8(p[4 * k + 0], s);
        q[1] = pack4i8(p[4 * k + 1], s);
        q[2] = pack4i8(p[4 * k + 2], s);
        q[3] = pack4i8(p[4 * k + 3], s);
        dst[k] = q;
    }
    return m;
}

// ROUND 24 = R23 (948us) with producers converted to i8 and EVACUATED from
// the C-SIMDs. R23 post-mortem: SGPR-chain null; VALUBusy 67->77 -> pack
// issue == LDS latency; wall = C-SIMD issue + producer contention. Issue
// ledger/phase: S0-2 = 2048 C-dot + ~1500 C-other + 1024 producer; S3 =
// 5120 producer f16 dot. Fix both: (a) producer dots i8 (rows 1024->512
// cyc), (b) ALL producer rows on SIMD3 (wv3 = Wih1 x4, wv7 = Wih2 x4,
// ~4500 cyc/phase < wall), (c) wv4/5/6 idle -> S0-2 run the latency
// chains UNCONTENDED. C waves write 1-byte/lane i8 h-rings (R22-verified
// conflict-free) for producer feed; f16 h0/h1 rings deleted; h2 f16 kept
// for FC. Precision: Wih path now i8 too -> predicted absmax 2-3e-3
// (pre-committed risk; revert producers to f16 if fail).
// Ledger: R16 neutral; R17 CU-halving dead; R18 cross-CU dead; R19
// per-step barrier dead; R20 pk_fma same-rate; R21 setprio null; R22 i8
// -2.6%; R23 SGPR-chain null (issue==latency trade).
__global__ __launch_bounds__(512)
__attribute__((amdgpu_waves_per_eu(2, 2)))
void lstm3_fused(
    const float* __restrict__ x,
    const float* __restrict__ Wih0, const float* __restrict__ Whh0,
    const float* __restrict__ bih0, const float* __restrict__ bhh0,
    const float* __restrict__ Wih1, const float* __restrict__ Whh1,
    const float* __restrict__ bih1, const float* __restrict__ bhh1,
    const float* __restrict__ Wih2, const float* __restrict__ Whh2,
    const float* __restrict__ bih2, const float* __restrict__ bhh2,
    const float* __restrict__ fcW,  const float* __restrict__ fcb,
    float* __restrict__ out)
{
    const int b   = blockIdx.x;
    const int tid = threadIdx.x;
    const int wv  = tid >> 6;          // 0..7 (wave-uniform role)
    const int L   = tid & 63;          // owned h-index / row-lane

    __shared__ __align__(16) signed char h0q[16][HID];   // i8: producer feed
    __shared__ __align__(16) signed char h1q[16][HID];
    __shared__ __align__(16) _Float16 h2ring[2][HID];    // f16: FC feed
    __shared__ float p1buf[2][WD][4][HID];               // wih1 partials
    __shared__ float p2buf[2][WD][4][HID];               // wih2 partials
    __shared__ __align__(16) float xs[T_LEN];

    // Stage x[b,0,:]; zero the rings.
    {
        const float4* xg4 = reinterpret_cast<const float4*>(x + b * T_LEN);
        reinterpret_cast<float4*>(xs)[tid] = xg4[tid];
        if (tid < 256) {
            reinterpret_cast<unsigned*>(h0q)[tid] = 0u;  // 1024B each
            reinterpret_cast<unsigned*>(h1q)[tid] = 0u;
        }
        if (tid < 64) reinterpret_cast<unsigned*>(h2ring)[tid] = 0u;
    }

    const float sI = -LOG2E, sF = -LOG2E, sG = -2.f * LOG2E, sO = -LOG2E;
    const float scl[4] = {sI, sF, sG, sO};

    uint4v wq[4][4];                   // i8 rows: C = whh; producers = wih
    float bias4[4] = {0.f, 0.f, 0.f, 0.f};
    float wx4[4]   = {0.f, 0.f, 0.f, 0.f};
    float fs4[4]   = {0.f, 0.f, 0.f, 0.f};

    if (wv < 3) {                      // C_l: whh_l all 4 gate rows, i8
        const float* Wh = (wv == 0) ? Whh0 : (wv == 1) ? Whh1 : Whh2;
        const float* bi = (wv == 0) ? bih0 : (wv == 1) ? bih1 : bih2;
        const float* bh = (wv == 0) ? bhh0 : (wv == 1) ? bhh1 : bhh2;
        #pragma unroll
        for (int c = 0; c < 4; ++c) {
            float m = quant_row(Wh + (c * 64 + L) * 64, wq[c]);
            fs4[c] = scl[c] * m * (1.f / (127.f * 127.f));
            bias4[c] = (bi[c * 64 + L] + bh[c * 64 + L]) * scl[c];
        }
        if (wv == 0) {
            #pragma unroll
            for (int c = 0; c < 4; ++c) wx4[c] = Wih0[c * 64 + L] * scl[c];
        }
    } else if (wv == 3 || wv == 7) {   // producer: full Wih_l, 4 rows/lane, i8
        const float* Wsrc = (wv == 3) ? Wih1 : Wih2;
        #pragma unroll
        for (int c = 0; c < 4; ++c) {
            float m = quant_row(Wsrc + (c * 64 + L) * 64, wq[c]);
            fs4[c] = scl[c] * m * (1.f / (127.f * 127.f));
        }
    }
    // wv 4,5,6: idle (barrier participants only).

    float cst = 0.f;                   // cell state (C waves, lane-local)
    int hs[16];                        // packed i8 h[t-1], wave-uniform
    #pragma unroll
    for (int k = 0; k < 16; ++k) hs[k] = 0;

    __syncthreads();

    for (int ph = 0; ph < NPH; ++ph) {
        const int par = ph & 1;

        if (wv == 0) {
            if (ph < NWIN) {           // h0 window ph
                const int tb = ph * WD;
                #pragma unroll
                for (int j = 0; j < WD; ++j) {
                    const int r = par * 8 + j;
                    float xv = xs[tb + j];
                    float d0 = dot64_i8s(wq[0], hs, fs4[0], fmaf(wx4[0], xv, bias4[0]));
                    float d1 = dot64_i8s(wq[1], hs, fs4[1], fmaf(wx4[1], xv, bias4[1]));
                    float d2 = dot64_i8s(wq[2], hs, fs4[2], fmaf(wx4[2], xv, bias4[2]));
                    float d3 = dot64_i8s(wq[3], hs, fs4[3], fmaf(wx4[3], xv, bias4[3]));
                    float ai = RCPF(1.f + EXP2F(d0));
                    float af = RCPF(1.f + EXP2F(d1));
                    float ag = fmaf(2.f, RCPF(1.f + EXP2F(d2)), -1.f);
                    float ao = RCPF(1.f + EXP2F(d3));
                    cst = fmaf(af, cst, ai * ag);
                    float tc = fmaf(2.f, RCPF(1.f + EXP2F(-2.f * LOG2E * cst)), -1.f);
                    float hf = ao * tc;
                    int qb = (int)rintf(hf * 127.f);
                    h0q[r][L] = (signed char)qb;       // producer feed
                    pack_hq(qb, L, hs);                // chain: regs only
                }
            }
        } else if (wv == 1) {
            if (ph >= 2 && ph < NWIN + 2) {    // h1 window ph-2 (p1[par] ready)
                const float (*pb)[4][HID] = p1buf[par];
                #pragma unroll
                for (int j = 0; j < WD; ++j) {
                    const int r = par * 8 + j;
                    float d0 = dot64_i8s(wq[0], hs, fs4[0], bias4[0] + pb[j][0][L]);
                    float d1 = dot64_i8s(wq[1], hs, fs4[1], bias4[1] + pb[j][1][L]);
                    float d2 = dot64_i8s(wq[2], hs, fs4[2], bias4[2] + pb[j][2][L]);
                    float d3 = dot64_i8s(wq[3], hs, fs4[3], bias4[3] + pb[j][3][L]);
                    float ai = RCPF(1.f + EXP2F(d0));
                    float af = RCPF(1.f + EXP2F(d1));
                    float ag = fmaf(2.f, RCPF(1.f + EXP2F(d2)), -1.f);
                    float ao = RCPF(1.f + EXP2F(d3));
                    cst = fmaf(af, cst, ai * ag);
                    float tc = fmaf(2.f, RCPF(1.f + EXP2F(-2.f * LOG2E * cst)), -1.f);
                    float hf = ao * tc;
                    int qb = (int)rintf(hf * 127.f);
                    h1q[r][L] = (signed char)qb;
                    pack_hq(qb, L, hs);
                }
            }
        } else if (wv == 2) {
            if (ph >= 4) {                     // h2 window ph-4 (p2[par] ready)
                const float (*pb)[4][HID] = p2buf[par];
                #pragma unroll
                for (int j = 0; j < WD; ++j) {
                    float d0 = dot64_i8s(wq[0], hs, fs4[0], bias4[0] + pb[j][0][L]);
                    float d1 = dot64_i8s(wq[1], hs, fs4[1], bias4[1] + pb[j][1][L]);
                    float d2 = dot64_i8s(wq[2], hs, fs4[2], bias4[2] + pb[j][2][L]);
                    float d3 = dot64_i8s(wq[3], hs, fs4[3], bias4[3] + pb[j][3][L]);
                    float ai = RCPF(1.f + EXP2F(d0));
                    float af = RCPF(1.f + EXP2F(d1));
                    float ag = fmaf(2.f, RCPF(1.f + EXP2F(d2)), -1.f);
                    float ao = RCPF(1.f + EXP2F(d3));
                    cst = fmaf(af, cst, ai * ag);
                    float tc = fmaf(2.f, RCPF(1.f + EXP2F(-2.f * LOG2E * cst)), -1.f);
                    float hf = ao * tc;
                    h2ring[j & 1][L] = (_Float16)hf;   // FC feed
                    int qb = (int)rintf(hf * 127.f);
                    pack_hq(qb, L, hs);
                }
            }
        } else if (wv == 3) {
            if (ph >= 1 && ph < NWIN + 1) {    // p1: Wih1 x h0 window ph-1
                float (*po)[4][HID] = p1buf[par ^ 1];
                const signed char* hw = &h0q[(par ^ 1) * 8][0];
                #pragma unroll
                for (int j = 0; j < WD; ++j) {
                    const uint4v* g = reinterpret_cast<const uint4v*>(hw + j * HID);
                    uint4v gq[4] = {g[0], g[1], g[2], g[3]};   // wave-uniform
                    po[j][0][L] = dot64_i8v(wq[0], gq, fs4[0]);
                    po[j][1][L] = dot64_i8v(wq[1], gq, fs4[1]);
                    po[j][2][L] = dot64_i8v(wq[2], gq, fs4[2]);
                    po[j][3][L] = dot64_i8v(wq[3], gq, fs4[3]);
                }
            }
        } else if (wv == 7) {
            if (ph >= 3 && ph < NWIN + 3) {    // p2: Wih2 x h1 window ph-3
                float (*po)[4][HID] = p2buf[par ^ 1];
                const signed char* hw = &h1q[(par ^ 1) * 8][0];
                #pragma unroll
                for (int j = 0; j < WD; ++j) {
                    const uint4v* g = reinterpret_cast<const uint4v*>(hw + j * HID);
                    uint4v gq[4] = {g[0], g[1], g[2], g[3]};
                    po[j][0][L] = dot64_i8v(wq[0], gq, fs4[0]);
                    po[j][1][L] = dot64_i8v(wq[1], gq, fs4[1]);
                    po[j][2][L] = dot64_i8v(wq[2], gq, fs4[2]);
                    po[j][3][L] = dot64_i8v(wq[3], gq, fs4[3]);
                }
            }
        }
        // wv 4,5,6: nothing — barrier only.

        __syncthreads();   // publish window: h rings + p-buffers
    }

    // Final FC (f32): h2[2047] -> slot 2047&1 = 1.
    if (tid < EMB) {
        float acc = fcb[tid];
        const _Float16* hf = &h2ring[1][0];
        const float4* W4 = reinterpret_cast<const float4*>(fcW + tid * HID);
        #pragma unroll
        for (int k = 0; k < 16; ++k) {
            float4 wv4 = W4[k];
            acc = fmaf(wv4.x, (float)hf[4 * k + 0], acc);
            acc = fmaf(wv4.y, (float)hf[4 * k + 1], acc);
            acc = fmaf(wv4.z, (float)hf[4 * k + 2], acc);
            acc = fmaf(wv4.w, (float)hf[4 * k + 3], acc);
        }
        out[b * EMB + tid] = acc;
    }
}

extern "C" void kernel_launch(void* const* d_in, const int* in_sizes, int n_in,
                              void* d_out, int out_size, void* d_ws, size_t ws_size,
                              hipStream_t stream) {
    const float* x    = (const float*)d_in[0];
    const float* Wih0 = (const float*)d_in[1];
    const float* Whh0 = (const float*)d_in[2];
    const float* bih0 = (const float*)d_in[3];
    const float* bhh0 = (const float*)d_in[4];
    const float* Wih1 = (const float*)d_in[5];
    const float* Whh1 = (const float*)d_in[6];
    const float* bih1 = (const float*)d_in[7];
    const float* bhh1 = (const float*)d_in[8];
    const float* Wih2 = (const float*)d_in[9];
    const float* Whh2 = (const float*)d_in[10];
    const float* bih2 = (const float*)d_in[11];
    const float* bhh2 = (const float*)d_in[12];
    const float* fcW  = (const float*)d_in[13];
    const float* fcb  = (const float*)d_in[14];
    float* out = (float*)d_out;

    lstm3_fused<<<dim3(256), dim3(512), 0, stream>>>(
        x, Wih0, Whh0, bih0, bhh0,
        Wih1, Whh1, bih1, bhh1,
        Wih2, Whh2, bih2, bhh2,
        fcW, fcb, out);
}